// Round 19
// baseline (85.930 us; speedup 1.0000x reference)
//
#include <hip/hip_runtime.h>

#define VNUM 6890
#define SLEN 20670      // V*3
#define NJ 24
#define NJR 19
#define NB 10
#define NROWS 219
#define NCOLS 480
#define RL 1440         // NCOLS*3
#define CCX_ELEMS (NROWS * RL)

#define MDIM 672
#define MT   21         // 32-row A granules
#define NT   2
#define KC   216        // k-chunks of 32
#define AROW 40         // 32 data + 8 pad, bf16
#define AIMG (32 * AROW)
#define BIMG (256 * AROW)

// gemm96: 96-row tiles, 12 K-splits of 18 chunks
#define MT2 7
#define KS2 12
#define KCP2 18
#define NGEMM (MT2 * NT * KS2)   // 168

#define NVCH 27         // v-chunks of 256 for fp32 rows 0/218
#define VPROW 1824      // 456 cols * 4 vals per chunk

typedef short short8 __attribute__((ext_vector_type(8)));
typedef unsigned short u16x4 __attribute__((ext_vector_type(4)));
typedef float f32x4 __attribute__((ext_vector_type(4)));

#define GLOAD_LDS16(g, l) \
    __builtin_amdgcn_global_load_lds((const __attribute__((address_space(1))) void*)(g), \
                                     (__attribute__((address_space(3))) void*)(l), 16, 0, 0)

__constant__ int c_PAR[24]  = {0,0,0,0,1,2,3,4,5,6,7,8,9,9,9,12,13,14,16,17,18,19,20,21};
__constant__ int c_LOFF[10] = {0,1,4,7,10,15,18,20,22,24};

__device__ __forceinline__ unsigned short f2bf(float f) {
    union { float f; unsigned int u; } x; x.f = f;
    unsigned int r = x.u + 0x7fffu + ((x.u >> 16) & 1u);   // RNE
    return (unsigned short)(r >> 16);
}

// ---------------------------------------------------------------------------
// prep: packA(0..223) | packB(224..439) | vchunk(440..466) | Jcols(467..490).
// (Verified rounds 13-18.)
// ---------------------------------------------------------------------------
__global__ __launch_bounds__(256) void prep(
    const float* __restrict__ vt, const float* __restrict__ sd,
    const float* __restrict__ pd, const float* __restrict__ Jreg,
    const float* __restrict__ jr, const float* __restrict__ w,
    unsigned short* __restrict__ Apack, unsigned short* __restrict__ Bpack,
    float* __restrict__ CCX, float* __restrict__ Jccx,
    float* __restrict__ vpart)
{
    __shared__ float jrl_b[256 * NJR];   // 19456 B
    __shared__ float wl_b[256 * NJ];     // 24576 B
    __shared__ float vtl[256 * 3];       //  3072 B

    const int bid = blockIdx.x;
    const int t = threadIdx.x;

    if (bid < 224) {
        const int r = bid;
        const float* src = (r == 0) ? vt
                         : (r <= 10 ? sd + (size_t)(r - 1) * SLEN
                         : (r <= 217 ? pd + (size_t)(r - 11) * SLEN : nullptr));
        for (int g = t; g < 1728; g += 256) {
            const int v = 4 * g;
            float lv[12];
            if (r <= 217) {
                if (3 * v + 12 <= SLEN) {
                    const float4 a = *reinterpret_cast<const float4*>(src + 3 * v);
                    const float4 b4 = *reinterpret_cast<const float4*>(src + 3 * v + 4);
                    const float4 c4 = *reinterpret_cast<const float4*>(src + 3 * v + 8);
                    lv[0]=a.x; lv[1]=a.y; lv[2]=a.z; lv[3]=a.w;
                    lv[4]=b4.x; lv[5]=b4.y; lv[6]=b4.z; lv[7]=b4.w;
                    lv[8]=c4.x; lv[9]=c4.y; lv[10]=c4.z; lv[11]=c4.w;
                } else {
                    #pragma unroll
                    for (int l = 0; l < 12; ++l) {
                        const int idx = 3 * v + l;
                        lv[l] = (idx < SLEN) ? src[idx] : 0.f;
                    }
                }
            } else if (r == 218) {
                #pragma unroll
                for (int l = 0; l < 12; ++l) lv[l] = (v + l / 3 < VNUM) ? 1.f : 0.f;
            } else {
                #pragma unroll
                for (int l = 0; l < 12; ++l) lv[l] = 0.f;
            }
            const int kc = v >> 5, kk = v & 31;
            #pragma unroll
            for (int c = 0; c < 3; ++c) {
                const int m = 3 * r + c;
                const int mt = m >> 5, mrow = m & 31;
                u16x4 s = {f2bf(lv[c]), f2bf(lv[3 + c]), f2bf(lv[6 + c]), f2bf(lv[9 + c])};
                *reinterpret_cast<u16x4*>(
                    &Apack[((size_t)(mt * KC + kc) * 32 + mrow) * AROW + kk]) = s;
            }
        }
    } else if (bid < 440) {
        const int kc = bid - 224;
        const int v0 = kc * 32;
        float* jrl = jrl_b;
        float* wl  = jrl_b + 32 * NJR;
        float* Jl2 = wl + 32 * NJ;
        for (int i = t; i < 32 * NJR; i += 256) {
            const int g = v0 * NJR + i;
            jrl[i] = (g < VNUM * NJR) ? jr[g] : 0.f;
        }
        for (int i = t; i < 32 * NJ; i += 256) {
            const int g = v0 * NJ + i;
            wl[i]  = (g < VNUM * NJ) ? w[g] : 0.f;
            Jl2[i] = (g < VNUM * NJ) ? Jreg[g] : 0.f;
        }
        __syncthreads();
        #pragma unroll
        for (int nt = 0; nt < NT; ++nt) {
            const int col = nt * 256 + t;
            const int j = col / 24, i = col - j * 24;
            short8 ov[4];
            #pragma unroll
            for (int kk = 0; kk < 32; ++kk) {
                float val = 0.f;
                if (v0 + kk < VNUM) {
                    if (col < 456)      val = jrl[kk * NJR + j] * wl[kk * NJ + i];
                    else if (col < 480) val = Jl2[kk * NJ + (col - 456)];
                }
                ov[kk >> 3][kk & 7] = (short)f2bf(val);
            }
            unsigned short* dst = Bpack + ((size_t)(nt * KC + kc) * 256 + t) * AROW;
            #pragma unroll
            for (int q = 0; q < 4; ++q)
                *reinterpret_cast<short8*>(dst + 8 * q) = ov[q];
        }
    } else if (bid < 467) {
        const int ch = bid - 440;
        const int v0 = ch * 256;
        for (int i = t; i < 256 * NJR; i += 256) {
            const int g = v0 * NJR + i;
            jrl_b[i] = (g < VNUM * NJR) ? jr[g] : 0.f;
        }
        for (int i = t; i < 256 * NJ; i += 256) {
            const int g = v0 * NJ + i;
            wl_b[i] = (g < VNUM * NJ) ? w[g] : 0.f;
        }
        for (int i = t; i < 256 * 3; i += 256) {
            const int g = v0 * 3 + i;
            vtl[i] = (g < VNUM * 3) ? vt[g] : 0.f;
        }
        __syncthreads();
        if (t < 228) {
            #pragma unroll
            for (int cc2 = 0; cc2 < 2; ++cc2) {
                const int col = t + cc2 * 228;
                const int j = col / 24, i2 = col - j * 24;
                float s0 = 0.f, s1 = 0.f, s2 = 0.f, s3 = 0.f;
                #pragma unroll 4
                for (int v = 0; v < 256; ++v) {
                    const float coef = jrl_b[v * NJR + j] * wl_b[v * NJ + i2];
                    s0 += coef * vtl[v * 3 + 0];
                    s1 += coef * vtl[v * 3 + 1];
                    s2 += coef * vtl[v * 3 + 2];
                    s3 += coef;
                }
                float4 pv = {s0, s1, s2, s3};
                *reinterpret_cast<float4*>(&vpart[(size_t)ch * VPROW + col * 4]) = pv;
            }
        }
    } else {
        const int jj = bid - 467;        // 0..23
        const int col = 456 + jj;
        float ja[34];
        #pragma unroll
        for (int k = 0; k < 34; ++k) ja[k] = 0.f;
        for (int v = t; v < VNUM; v += 256) {
            const float coef = Jreg[v * NJ + jj];
            ja[33] += coef;
            #pragma unroll
            for (int c = 0; c < 3; ++c) ja[c] += coef * vt[3 * v + c];
            #pragma unroll
            for (int r = 1; r <= 10; ++r)
                #pragma unroll
                for (int c = 0; c < 3; ++c)
                    ja[r * 3 + c] += coef * sd[(size_t)(r - 1) * SLEN + 3 * v + c];
        }
        float* red = jrl_b;              // [4][34]
        #pragma unroll
        for (int k = 0; k < 34; ++k) {
            float vv = ja[k];
            #pragma unroll
            for (int off = 32; off; off >>= 1) vv += __shfl_down(vv, off);
            if ((t & 63) == 0) red[(t >> 6) * 34 + k] = vv;
        }
        __syncthreads();
        if (t == 0) {
            #pragma unroll
            for (int k = 0; k < 34; ++k) {
                const float s = red[0 * 34 + k] + red[1 * 34 + k]
                              + red[2 * 34 + k] + red[3 * 34 + k];
                if (k < 33) {
                    const int r = k / 3, c = k - (k / 3) * 3;
                    Jccx[r * 72 + jj * 3 + c] = s;
                    if (r == 0) CCX[col * 3 + c] = s;
                } else {
                    CCX[(size_t)218 * RL + col * 3 + 0] = s;
                    CCX[(size_t)218 * RL + col * 3 + 1] = s;
                    CCX[(size_t)218 * RL + col * 3 + 2] = s;
                }
            }
        }
    }
}

// ---------------------------------------------------------------------------
// gemmchain: bid<168 GEMM | bid 168..175 vred | bid 176..687 chain.
// (Verified rounds 13-18.)
// ---------------------------------------------------------------------------
__global__ __launch_bounds__(256) void gemmchain(
    const unsigned short* __restrict__ Apack,
    const unsigned short* __restrict__ Bpack,
    float* __restrict__ partials,
    const float* __restrict__ vpart, float* __restrict__ CCX,
    const float* __restrict__ beta, const float* __restrict__ theta,
    const float* __restrict__ Jccx,
    float* __restrict__ xs_ws, float* __restrict__ Rg_ws, float* __restrict__ tA_ws)
{
    __shared__ __align__(16) char smem[2 * 7680 + 2 * 20480];   // 56320
    const int bid = blockIdx.x;
    const int t = threadIdx.x;

    if (bid >= NGEMM) {
        if (bid < NGEMM + 8) {
            const int tid = (bid - NGEMM) * 256 + t;
            if (tid < 456 * 4) {
                float s = 0.f;
                #pragma unroll 9
                for (int ch = 0; ch < NVCH; ++ch)
                    s += vpart[(size_t)ch * VPROW + tid];
                const int col = tid >> 2, q = tid & 3;
                if (q < 3) {
                    CCX[col * 3 + q] = s;
                } else {
                    CCX[(size_t)218 * RL + col * 3 + 0] = s;
                    CCX[(size_t)218 * RL + col * 3 + 1] = s;
                    CCX[(size_t)218 * RL + col * 3 + 2] = s;
                }
            }
            return;
        }
        float* F = (float*)smem;
        float* xs = F;                       // 218
        float (*Rl)[9] = (float(*)[9])(F + 224);
        float (*Rg)[9] = (float(*)[9])(F + 440);
        float (*tg)[3] = (float(*)[3])(F + 656);
        float (*tA)[3] = (float(*)[3])(F + 728);
        float (*Jl)[3] = (float(*)[3])(F + 800);
        const int b = bid - (NGEMM + 8);

        if (t < 24) {
            const int i = t;
            const float tx = theta[b * 72 + 3 * i + 0];
            const float ty = theta[b * 72 + 3 * i + 1];
            const float tz = theta[b * 72 + 3 * i + 2];
            const float ax = tx + 1e-8f, ay = ty + 1e-8f, az = tz + 1e-8f;
            const float angle = sqrtf(ax * ax + ay * ay + az * az);
            const float half = 0.5f * angle;
            const float sh = sinf(half), chh = cosf(half);
            const float inv = 1.f / angle;
            float qw = chh, qx = sh * tx * inv, qy = sh * ty * inv, qz = sh * tz * inv;
            const float rn = 1.f / sqrtf(qw * qw + qx * qx + qy * qy + qz * qz);
            qw *= rn; qx *= rn; qy *= rn; qz *= rn;
            float R[9];
            R[0] = 1.f - 2.f * (qy * qy + qz * qz);
            R[1] = 2.f * (qx * qy - qw * qz);
            R[2] = 2.f * (qx * qz + qw * qy);
            R[3] = 2.f * (qx * qy + qw * qz);
            R[4] = 1.f - 2.f * (qx * qx + qz * qz);
            R[5] = 2.f * (qy * qz - qw * qx);
            R[6] = 2.f * (qx * qz - qw * qy);
            R[7] = 2.f * (qy * qz + qw * qx);
            R[8] = 1.f - 2.f * (qx * qx + qy * qy);
            #pragma unroll
            for (int e = 0; e < 9; ++e) Rl[i][e] = R[e];
            if (i >= 1) {
                #pragma unroll
                for (int e = 0; e < 9; ++e)
                    xs[11 + (i - 1) * 9 + e] = R[e] - ((e == 0 || e == 4 || e == 8) ? 1.f : 0.f);
            }
        } else if (t == 24) {
            xs[0] = 1.f;
        } else if (t >= 25 && t < 35) {
            xs[t - 24] = beta[b * NB + (t - 25)];
        }
        __syncthreads();

        if (t < 72) {
            const int jj = t / 3, c = t - (t / 3) * 3;
            float a = 0.f;
            #pragma unroll
            for (int r = 0; r <= 10; ++r)
                a += xs[r] * Jccx[r * 72 + jj * 3 + c];
            Jl[jj][c] = a;
        }
        __syncthreads();

        for (int lv = 0; lv < 9; ++lv) {
            const int beg = c_LOFF[lv];
            const int cnt = c_LOFF[lv + 1] - beg;
            if (t < cnt * 12) {
                const int li = t / 12, e = t - li * 12;
                const int j = beg + li;
                const int r = e >> 2, cc = e & 3;
                if (lv == 0) {
                    if (cc < 3) Rg[0][r * 3 + cc] = Rl[0][r * 3 + cc] * ((cc == 0) ? 1.f : -1.f);
                    else        tg[0][r] = Jl[0][r];
                } else {
                    const int p = c_PAR[j];
                    if (cc < 3) {
                        Rg[j][r * 3 + cc] = Rg[p][r * 3 + 0] * Rl[j][0 + cc]
                                          + Rg[p][r * 3 + 1] * Rl[j][3 + cc]
                                          + Rg[p][r * 3 + 2] * Rl[j][6 + cc];
                    } else {
                        const float t0 = Jl[j][0] - Jl[p][0];
                        const float t1 = Jl[j][1] - Jl[p][1];
                        const float t2 = Jl[j][2] - Jl[p][2];
                        tg[j][r] = Rg[p][r * 3 + 0] * t0 + Rg[p][r * 3 + 1] * t1
                                 + Rg[p][r * 3 + 2] * t2 + tg[p][r];
                    }
                }
            }
            __syncthreads();
        }

        if (t < 72) {
            const int i = t / 3, c = t - (t / 3) * 3;
            tA[i][c] = tg[i][c] - (Rg[i][c * 3 + 0] * Jl[i][0]
                                 + Rg[i][c * 3 + 1] * Jl[i][1]
                                 + Rg[i][c * 3 + 2] * Jl[i][2]);
        }
        __syncthreads();

        if (t < 218) xs_ws[(size_t)b * 218 + t] = xs[t];
        if (t < 216) Rg_ws[(size_t)b * 216 + t] = ((const float*)Rg)[t];
        if (t < 72)  tA_ws[(size_t)b * 72 + t]  = ((const float*)tA)[t];
        return;
    }

    // ------------------------------ GEMM ----------------------------------
    const int ks = bid % KS2;
    const int nt = (bid / KS2) & 1;
    const int mt2 = bid / (KS2 * NT);
    const int w4 = t >> 6;
    const int lane15 = t & 15;
    const int kg = (t >> 4) & 3;
    const int kc0 = ks * KCP2;

    f32x4 acc[6][4];
    #pragma unroll
    for (int mf = 0; mf < 6; ++mf)
        #pragma unroll
        for (int nf = 0; nf < 4; ++nf) acc[mf][nf] = (f32x4){0.f, 0.f, 0.f, 0.f};

#define STAGE2(kc, buf) do { \
        _Pragma("unroll") \
        for (int q = 0; q < 3; ++q) { \
            if (t < 160) \
                GLOAD_LDS16((const char*)Apack + ((size_t)((3 * mt2 + q) * KC + (kc))) * 2560 + t * 16, \
                            smem + (buf) * 7680 + q * 2560 + (t >> 6) * 1024); \
        } \
        _Pragma("unroll") \
        for (int it = 0; it < 5; ++it) \
            GLOAD_LDS16((const char*)Bpack + ((size_t)(nt * KC + (kc))) * 20480 + (it * 256 + t) * 16, \
                        smem + 15360 + (buf) * 20480 + it * 4096 + (t >> 6) * 1024); \
    } while (0)

    STAGE2(kc0, 0);
    asm volatile("s_waitcnt vmcnt(0)" ::: "memory");
    __syncthreads();

    for (int i = 0; i < KCP2; ++i) {
        const int cur = i & 1;
        if (i < KCP2 - 1) STAGE2(kc0 + i + 1, cur ^ 1);

        short8 af[6];
        #pragma unroll
        for (int mf = 0; mf < 6; ++mf)
            af[mf] = *reinterpret_cast<const short8*>(
                smem + cur * 7680 + (mf * 16 + lane15) * 80 + kg * 16);
        #pragma unroll
        for (int nf = 0; nf < 4; ++nf) {
            const short8 bf = *reinterpret_cast<const short8*>(
                smem + 15360 + cur * 20480 + (w4 * 64 + nf * 16 + lane15) * 80 + kg * 16);
            #pragma unroll
            for (int mf = 0; mf < 6; ++mf)
                acc[mf][nf] = __builtin_amdgcn_mfma_f32_16x16x32_bf16(af[mf], bf, acc[mf][nf], 0, 0, 0);
        }
        if (i < KCP2 - 1) {
            asm volatile("s_waitcnt vmcnt(0)" ::: "memory");
            __syncthreads();
        }
    }
#undef STAGE2

    #pragma unroll
    for (int mf = 0; mf < 6; ++mf)
        #pragma unroll
        for (int nf = 0; nf < 4; ++nf) {
            const int m = mt2 * 96 + mf * 16 + kg * 4;
            const int col = nt * 256 + w4 * 64 + nf * 16 + lane15;
            #pragma unroll
            for (int reg = 0; reg < 4; ++reg)
                partials[((size_t)ks * MDIM + m + reg) * 512 + col] = acc[mf][nf][reg];
        }
}

// ---------------------------------------------------------------------------
// reduce: 336 blocks; sum 12 K-splits -> CCX rows 1..217. (Verified.)
// ---------------------------------------------------------------------------
__global__ __launch_bounds__(256) void reduce_k(
    const float* __restrict__ partials, float* __restrict__ CCX)
{
    const int idx = blockIdx.x * 256 + threadIdx.x;
    const int m = idx >> 7;
    const int col = (idx & 127) * 4;
    float4 s = {0.f, 0.f, 0.f, 0.f};
    #pragma unroll 6
    for (int ks = 0; ks < KS2; ++ks) {
        const float4 p = *reinterpret_cast<const float4*>(
            &partials[((size_t)ks * MDIM + m) * 512 + col]);
        s.x += p.x; s.y += p.y; s.z += p.z; s.w += p.w;
    }
    if (m < 657 && col < NCOLS) {
        const int r = m / 3, c = m - (m / 3) * 3;
        if (r != 0 && r != 218) {
            float sv[4] = {s.x, s.y, s.z, s.w};
            #pragma unroll
            for (int u = 0; u < 4; ++u)
                CCX[(size_t)r * RL + (col + u) * 3 + c] = sv[u];
        }
    }
}

// ---------------------------------------------------------------------------
// mgemm (ROUND-19): bgroup 16 @ 512 threads. Grid 192 blocks x 8 waves =
// 2 blocks/CU = 16 waves/CU (same wave occupancy as r16/r18; r17's loss was
// its 192x256 grid = 4 waves/CU on half the CUs). Thread halves own b 0..7 /
// 8..15 over the SAME staged cl tile -> CCX traffic 76 -> 40MB (BW theory).
// Double-buffered 16-row chunks; 1024 float4/chunk => 2 GLOAD_LDS16/thread.
// Padded reads reach CCX row <=225 (spill into partials, never consumed).
// LDS 13952 + 32768 = 46720 B -> 2 blocks/CU fits.
// ---------------------------------------------------------------------------
__global__ __launch_bounds__(512) void mgemm(
    const float* __restrict__ xs_ws, const float* __restrict__ CCX,
    float* __restrict__ Ml)
{
    __shared__ float xsl[16 * 218];                   // 13952 B
    __shared__ __align__(16) float cl[2][4096];       // 2 x 16384 B
    const int cg = blockIdx.x % 6;
    const int b0 = (blockIdx.x / 6) * 16;
    const int t = threadIdx.x;
    const int colbase = cg * 228;
    const int half = t >> 8;       // 0: b0..b0+7, 1: b0+8..b0+15
    const int u = t & 255;         // col index (active if < 228)

    for (int i = t; i < 16 * 218; i += 512)
        xsl[i] = xs_ws[(size_t)b0 * 218 + i];

    float a8[8];
    #pragma unroll
    for (int bl = 0; bl < 8; ++bl) a8[bl] = 0.f;

#define MSTAGE(c, buf) do { \
        const int rbase_ = (c) * 16; \
        _Pragma("unroll") \
        for (int k = 0; k < 2; ++k) { \
            const int i_ = t + k * 512; \
            const int rl_ = i_ / 57; \
            const int q_ = i_ - rl_ * 57; \
            GLOAD_LDS16(CCX + (size_t)(rbase_ + rl_) * RL + colbase + q_ * 4, \
                        (char*)cl[buf] + (size_t)i_ * 16); \
        } \
    } while (0)

    MSTAGE(0, 0);

    for (int c = 0; c < 14; ++c) {
        const int cur = c & 1;
        asm volatile("s_waitcnt vmcnt(0)" ::: "memory");
        __syncthreads();                      // cl[cur] ready; prior reads done
        if (c < 13) MSTAGE(c + 1, cur ^ 1);   // async: lands during compute below
        const int rbase = c * 16;
        const int rn = (218 - rbase < 16) ? (218 - rbase) : 16;
        if (u < 228) {
            for (int rl = 0; rl < rn; ++rl) {
                const float cv = cl[cur][rl * 228 + u];
                #pragma unroll
                for (int bl = 0; bl < 8; ++bl)
                    a8[bl] += xsl[(half * 8 + bl) * 218 + rbase + rl] * cv;
            }
        }
        __syncthreads();                      // cl[cur] reads done before reuse
    }
#undef MSTAGE

    if (u < 228) {
        #pragma unroll
        for (int bl = 0; bl < 8; ++bl)
            Ml[(size_t)(b0 + half * 8 + bl) * 1368 + colbase + u] = a8[bl];
    }
}

// ---------------------------------------------------------------------------
// joints: one block per b, 256 threads. (Verified.)
// ---------------------------------------------------------------------------
__global__ __launch_bounds__(256) void joints_k(
    const float* __restrict__ Ml, const float* __restrict__ Rg_ws,
    const float* __restrict__ tA_ws, const float* __restrict__ CCX,
    float* __restrict__ out)
{
    __shared__ float Mls[1368];
    __shared__ float Wj[1368];
    __shared__ float Rgs[216];
    __shared__ float tAs[72];
    const int b = blockIdx.x;
    const int t = threadIdx.x;

    for (int i = t; i < 342; i += 256) {
        reinterpret_cast<float4*>(Mls)[i] =
            reinterpret_cast<const float4*>(Ml + (size_t)b * 1368)[i];
        reinterpret_cast<float4*>(Wj)[i] =
            reinterpret_cast<const float4*>(CCX + (size_t)218 * RL)[i];
    }
    if (t < 216) Rgs[t] = Rg_ws[(size_t)b * 216 + t];
    if (t < 72)  tAs[t] = tA_ws[(size_t)b * 72 + t];
    __syncthreads();

    if (t < 57) {
        const int j = t / 3, c = t - (t / 3) * 3;
        float a = 0.f;
        #pragma unroll
        for (int i = 0; i < 24; ++i) {
            const int mb = (j * 24 + i) * 3;
            a += Rgs[i * 9 + c * 3 + 0] * Mls[mb + 0]
               + Rgs[i * 9 + c * 3 + 1] * Mls[mb + 1]
               + Rgs[i * 9 + c * 3 + 2] * Mls[mb + 2]
               + tAs[i * 3 + c] * Wj[mb];
        }
        out[b * 57 + t] = a;
    }
}

extern "C" void kernel_launch(void* const* d_in, const int* in_sizes, int n_in,
                              void* d_out, int out_size, void* d_ws, size_t ws_size,
                              hipStream_t stream) {
    const float* beta  = (const float*)d_in[0];
    const float* theta = (const float*)d_in[1];
    const float* vt    = (const float*)d_in[2];
    const float* sd    = (const float*)d_in[3];
    const float* pd    = (const float*)d_in[4];
    const float* Jreg  = (const float*)d_in[5];
    const float* jr    = (const float*)d_in[6];
    const float* w     = (const float*)d_in[7];
    float* outp = (float*)d_out;

    // ws layout (floats): CCX | partials(12) | Apack | Bpack | Jccx | xs | Rg | tA | vpart | Ml
    float* CCX = (float*)d_ws;
    float* partials = CCX + CCX_ELEMS;
    unsigned short* Apack = (unsigned short*)(partials + (size_t)KS2 * MDIM * 512);
    unsigned short* Bpack = Apack + (size_t)MT * KC * AIMG;
    float* Jccx  = (float*)(Bpack + (size_t)NT * KC * BIMG);
    float* xs_ws = Jccx + 792;
    float* Rg_ws = xs_ws + 512 * 218;
    float* tA_ws = Rg_ws + 512 * 216;
    float* vpart = tA_ws + 512 * 72;
    float* Ml    = vpart + (size_t)NVCH * VPROW;

    prep<<<491, 256, 0, stream>>>(vt, sd, pd, Jreg, jr, w, Apack, Bpack, CCX, Jccx, vpart);
    gemmchain<<<NGEMM + 8 + 512, 256, 0, stream>>>(Apack, Bpack, partials, vpart, CCX,
                                                   beta, theta, Jccx,
                                                   xs_ws, Rg_ws, tA_ws);
    reduce_k<<<336, 256, 0, stream>>>(partials, CCX);
    mgemm<<<192, 512, 0, stream>>>(xs_ws, CCX, Ml);
    joints_k<<<512, 256, 0, stream>>>(Ml, Rg_ws, tA_ws, CCX, outp);
}

// Round 20
// 81.198 us; speedup vs baseline: 1.0583x; 1.0583x over previous
//
#include <hip/hip_runtime.h>

#define VNUM 6890
#define SLEN 20670      // V*3
#define NJ 24
#define NJR 19
#define NB 10
#define NROWS 219
#define NCOLS 480
#define RL 1440         // NCOLS*3
#define CCX_ELEMS (NROWS * RL)

#define MDIM 672
#define MT   21         // 32-row A granules
#define NT   2
#define KC   216        // k-chunks of 32
#define AROW 40         // 32 data + 8 pad, bf16
#define AIMG (32 * AROW)
#define BIMG (256 * AROW)

// gemm96: 96-row tiles, 12 K-splits of 18 chunks
#define MT2 7
#define KS2 12
#define KCP2 18
#define NGEMM (MT2 * NT * KS2)   // 168

#define NVCH 27         // v-chunks of 256 for fp32 rows 0/218
#define VPROW 1824      // 456 cols * 4 vals per chunk

typedef short short8 __attribute__((ext_vector_type(8)));
typedef unsigned short u16x4 __attribute__((ext_vector_type(4)));
typedef float f32x4 __attribute__((ext_vector_type(4)));

#define GLOAD_LDS16(g, l) \
    __builtin_amdgcn_global_load_lds((const __attribute__((address_space(1))) void*)(g), \
                                     (__attribute__((address_space(3))) void*)(l), 16, 0, 0)

__constant__ int c_PAR[24]  = {0,0,0,0,1,2,3,4,5,6,7,8,9,9,9,12,13,14,16,17,18,19,20,21};
__constant__ int c_LOFF[10] = {0,1,4,7,10,15,18,20,22,24};

__device__ __forceinline__ unsigned short f2bf(float f) {
    union { float f; unsigned int u; } x; x.f = f;
    unsigned int r = x.u + 0x7fffu + ((x.u >> 16) & 1u);   // RNE
    return (unsigned short)(r >> 16);
}

// ---------------------------------------------------------------------------
// prep: packA(0..223) | packB(224..439) | vchunk(440..466) | Jcols(467..490).
// (Verified rounds 13-19.)
// ---------------------------------------------------------------------------
__global__ __launch_bounds__(256) void prep(
    const float* __restrict__ vt, const float* __restrict__ sd,
    const float* __restrict__ pd, const float* __restrict__ Jreg,
    const float* __restrict__ jr, const float* __restrict__ w,
    unsigned short* __restrict__ Apack, unsigned short* __restrict__ Bpack,
    float* __restrict__ CCX, float* __restrict__ Jccx,
    float* __restrict__ vpart)
{
    __shared__ float jrl_b[256 * NJR];   // 19456 B
    __shared__ float wl_b[256 * NJ];     // 24576 B
    __shared__ float vtl[256 * 3];       //  3072 B

    const int bid = blockIdx.x;
    const int t = threadIdx.x;

    if (bid < 224) {
        const int r = bid;
        const float* src = (r == 0) ? vt
                         : (r <= 10 ? sd + (size_t)(r - 1) * SLEN
                         : (r <= 217 ? pd + (size_t)(r - 11) * SLEN : nullptr));
        for (int g = t; g < 1728; g += 256) {
            const int v = 4 * g;
            float lv[12];
            if (r <= 217) {
                if (3 * v + 12 <= SLEN) {
                    const float4 a = *reinterpret_cast<const float4*>(src + 3 * v);
                    const float4 b4 = *reinterpret_cast<const float4*>(src + 3 * v + 4);
                    const float4 c4 = *reinterpret_cast<const float4*>(src + 3 * v + 8);
                    lv[0]=a.x; lv[1]=a.y; lv[2]=a.z; lv[3]=a.w;
                    lv[4]=b4.x; lv[5]=b4.y; lv[6]=b4.z; lv[7]=b4.w;
                    lv[8]=c4.x; lv[9]=c4.y; lv[10]=c4.z; lv[11]=c4.w;
                } else {
                    #pragma unroll
                    for (int l = 0; l < 12; ++l) {
                        const int idx = 3 * v + l;
                        lv[l] = (idx < SLEN) ? src[idx] : 0.f;
                    }
                }
            } else if (r == 218) {
                #pragma unroll
                for (int l = 0; l < 12; ++l) lv[l] = (v + l / 3 < VNUM) ? 1.f : 0.f;
            } else {
                #pragma unroll
                for (int l = 0; l < 12; ++l) lv[l] = 0.f;
            }
            const int kc = v >> 5, kk = v & 31;
            #pragma unroll
            for (int c = 0; c < 3; ++c) {
                const int m = 3 * r + c;
                const int mt = m >> 5, mrow = m & 31;
                u16x4 s = {f2bf(lv[c]), f2bf(lv[3 + c]), f2bf(lv[6 + c]), f2bf(lv[9 + c])};
                *reinterpret_cast<u16x4*>(
                    &Apack[((size_t)(mt * KC + kc) * 32 + mrow) * AROW + kk]) = s;
            }
        }
    } else if (bid < 440) {
        const int kc = bid - 224;
        const int v0 = kc * 32;
        float* jrl = jrl_b;
        float* wl  = jrl_b + 32 * NJR;
        float* Jl2 = wl + 32 * NJ;
        for (int i = t; i < 32 * NJR; i += 256) {
            const int g = v0 * NJR + i;
            jrl[i] = (g < VNUM * NJR) ? jr[g] : 0.f;
        }
        for (int i = t; i < 32 * NJ; i += 256) {
            const int g = v0 * NJ + i;
            wl[i]  = (g < VNUM * NJ) ? w[g] : 0.f;
            Jl2[i] = (g < VNUM * NJ) ? Jreg[g] : 0.f;
        }
        __syncthreads();
        #pragma unroll
        for (int nt = 0; nt < NT; ++nt) {
            const int col = nt * 256 + t;
            const int j = col / 24, i = col - j * 24;
            short8 ov[4];
            #pragma unroll
            for (int kk = 0; kk < 32; ++kk) {
                float val = 0.f;
                if (v0 + kk < VNUM) {
                    if (col < 456)      val = jrl[kk * NJR + j] * wl[kk * NJ + i];
                    else if (col < 480) val = Jl2[kk * NJ + (col - 456)];
                }
                ov[kk >> 3][kk & 7] = (short)f2bf(val);
            }
            unsigned short* dst = Bpack + ((size_t)(nt * KC + kc) * 256 + t) * AROW;
            #pragma unroll
            for (int q = 0; q < 4; ++q)
                *reinterpret_cast<short8*>(dst + 8 * q) = ov[q];
        }
    } else if (bid < 467) {
        const int ch = bid - 440;
        const int v0 = ch * 256;
        for (int i = t; i < 256 * NJR; i += 256) {
            const int g = v0 * NJR + i;
            jrl_b[i] = (g < VNUM * NJR) ? jr[g] : 0.f;
        }
        for (int i = t; i < 256 * NJ; i += 256) {
            const int g = v0 * NJ + i;
            wl_b[i] = (g < VNUM * NJ) ? w[g] : 0.f;
        }
        for (int i = t; i < 256 * 3; i += 256) {
            const int g = v0 * 3 + i;
            vtl[i] = (g < VNUM * 3) ? vt[g] : 0.f;
        }
        __syncthreads();
        if (t < 228) {
            #pragma unroll
            for (int cc2 = 0; cc2 < 2; ++cc2) {
                const int col = t + cc2 * 228;
                const int j = col / 24, i2 = col - j * 24;
                float s0 = 0.f, s1 = 0.f, s2 = 0.f, s3 = 0.f;
                #pragma unroll 4
                for (int v = 0; v < 256; ++v) {
                    const float coef = jrl_b[v * NJR + j] * wl_b[v * NJ + i2];
                    s0 += coef * vtl[v * 3 + 0];
                    s1 += coef * vtl[v * 3 + 1];
                    s2 += coef * vtl[v * 3 + 2];
                    s3 += coef;
                }
                float4 pv = {s0, s1, s2, s3};
                *reinterpret_cast<float4*>(&vpart[(size_t)ch * VPROW + col * 4]) = pv;
            }
        }
    } else {
        const int jj = bid - 467;        // 0..23
        const int col = 456 + jj;
        float ja[34];
        #pragma unroll
        for (int k = 0; k < 34; ++k) ja[k] = 0.f;
        for (int v = t; v < VNUM; v += 256) {
            const float coef = Jreg[v * NJ + jj];
            ja[33] += coef;
            #pragma unroll
            for (int c = 0; c < 3; ++c) ja[c] += coef * vt[3 * v + c];
            #pragma unroll
            for (int r = 1; r <= 10; ++r)
                #pragma unroll
                for (int c = 0; c < 3; ++c)
                    ja[r * 3 + c] += coef * sd[(size_t)(r - 1) * SLEN + 3 * v + c];
        }
        float* red = jrl_b;              // [4][34]
        #pragma unroll
        for (int k = 0; k < 34; ++k) {
            float vv = ja[k];
            #pragma unroll
            for (int off = 32; off; off >>= 1) vv += __shfl_down(vv, off);
            if ((t & 63) == 0) red[(t >> 6) * 34 + k] = vv;
        }
        __syncthreads();
        if (t == 0) {
            #pragma unroll
            for (int k = 0; k < 34; ++k) {
                const float s = red[0 * 34 + k] + red[1 * 34 + k]
                              + red[2 * 34 + k] + red[3 * 34 + k];
                if (k < 33) {
                    const int r = k / 3, c = k - (k / 3) * 3;
                    Jccx[r * 72 + jj * 3 + c] = s;
                    if (r == 0) CCX[col * 3 + c] = s;
                } else {
                    CCX[(size_t)218 * RL + col * 3 + 0] = s;
                    CCX[(size_t)218 * RL + col * 3 + 1] = s;
                    CCX[(size_t)218 * RL + col * 3 + 2] = s;
                }
            }
        }
    }
}

// ---------------------------------------------------------------------------
// gemmchain: bid<168 GEMM | bid 168..175 vred | bid 176..687 chain.
// (Verified rounds 13-19.)
// ---------------------------------------------------------------------------
__global__ __launch_bounds__(256) void gemmchain(
    const unsigned short* __restrict__ Apack,
    const unsigned short* __restrict__ Bpack,
    float* __restrict__ partials,
    const float* __restrict__ vpart, float* __restrict__ CCX,
    const float* __restrict__ beta, const float* __restrict__ theta,
    const float* __restrict__ Jccx,
    float* __restrict__ xs_ws, float* __restrict__ Rg_ws, float* __restrict__ tA_ws)
{
    __shared__ __align__(16) char smem[2 * 7680 + 2 * 20480];   // 56320
    const int bid = blockIdx.x;
    const int t = threadIdx.x;

    if (bid >= NGEMM) {
        if (bid < NGEMM + 8) {
            const int tid = (bid - NGEMM) * 256 + t;
            if (tid < 456 * 4) {
                float s = 0.f;
                #pragma unroll 9
                for (int ch = 0; ch < NVCH; ++ch)
                    s += vpart[(size_t)ch * VPROW + tid];
                const int col = tid >> 2, q = tid & 3;
                if (q < 3) {
                    CCX[col * 3 + q] = s;
                } else {
                    CCX[(size_t)218 * RL + col * 3 + 0] = s;
                    CCX[(size_t)218 * RL + col * 3 + 1] = s;
                    CCX[(size_t)218 * RL + col * 3 + 2] = s;
                }
            }
            return;
        }
        float* F = (float*)smem;
        float* xs = F;                       // 218
        float (*Rl)[9] = (float(*)[9])(F + 224);
        float (*Rg)[9] = (float(*)[9])(F + 440);
        float (*tg)[3] = (float(*)[3])(F + 656);
        float (*tA)[3] = (float(*)[3])(F + 728);
        float (*Jl)[3] = (float(*)[3])(F + 800);
        const int b = bid - (NGEMM + 8);

        if (t < 24) {
            const int i = t;
            const float tx = theta[b * 72 + 3 * i + 0];
            const float ty = theta[b * 72 + 3 * i + 1];
            const float tz = theta[b * 72 + 3 * i + 2];
            const float ax = tx + 1e-8f, ay = ty + 1e-8f, az = tz + 1e-8f;
            const float angle = sqrtf(ax * ax + ay * ay + az * az);
            const float half = 0.5f * angle;
            const float sh = sinf(half), chh = cosf(half);
            const float inv = 1.f / angle;
            float qw = chh, qx = sh * tx * inv, qy = sh * ty * inv, qz = sh * tz * inv;
            const float rn = 1.f / sqrtf(qw * qw + qx * qx + qy * qy + qz * qz);
            qw *= rn; qx *= rn; qy *= rn; qz *= rn;
            float R[9];
            R[0] = 1.f - 2.f * (qy * qy + qz * qz);
            R[1] = 2.f * (qx * qy - qw * qz);
            R[2] = 2.f * (qx * qz + qw * qy);
            R[3] = 2.f * (qx * qy + qw * qz);
            R[4] = 1.f - 2.f * (qx * qx + qz * qz);
            R[5] = 2.f * (qy * qz - qw * qx);
            R[6] = 2.f * (qx * qz - qw * qy);
            R[7] = 2.f * (qy * qz + qw * qx);
            R[8] = 1.f - 2.f * (qx * qx + qy * qy);
            #pragma unroll
            for (int e = 0; e < 9; ++e) Rl[i][e] = R[e];
            if (i >= 1) {
                #pragma unroll
                for (int e = 0; e < 9; ++e)
                    xs[11 + (i - 1) * 9 + e] = R[e] - ((e == 0 || e == 4 || e == 8) ? 1.f : 0.f);
            }
        } else if (t == 24) {
            xs[0] = 1.f;
        } else if (t >= 25 && t < 35) {
            xs[t - 24] = beta[b * NB + (t - 25)];
        }
        __syncthreads();

        if (t < 72) {
            const int jj = t / 3, c = t - (t / 3) * 3;
            float a = 0.f;
            #pragma unroll
            for (int r = 0; r <= 10; ++r)
                a += xs[r] * Jccx[r * 72 + jj * 3 + c];
            Jl[jj][c] = a;
        }
        __syncthreads();

        for (int lv = 0; lv < 9; ++lv) {
            const int beg = c_LOFF[lv];
            const int cnt = c_LOFF[lv + 1] - beg;
            if (t < cnt * 12) {
                const int li = t / 12, e = t - li * 12;
                const int j = beg + li;
                const int r = e >> 2, cc = e & 3;
                if (lv == 0) {
                    if (cc < 3) Rg[0][r * 3 + cc] = Rl[0][r * 3 + cc] * ((cc == 0) ? 1.f : -1.f);
                    else        tg[0][r] = Jl[0][r];
                } else {
                    const int p = c_PAR[j];
                    if (cc < 3) {
                        Rg[j][r * 3 + cc] = Rg[p][r * 3 + 0] * Rl[j][0 + cc]
                                          + Rg[p][r * 3 + 1] * Rl[j][3 + cc]
                                          + Rg[p][r * 3 + 2] * Rl[j][6 + cc];
                    } else {
                        const float t0 = Jl[j][0] - Jl[p][0];
                        const float t1 = Jl[j][1] - Jl[p][1];
                        const float t2 = Jl[j][2] - Jl[p][2];
                        tg[j][r] = Rg[p][r * 3 + 0] * t0 + Rg[p][r * 3 + 1] * t1
                                 + Rg[p][r * 3 + 2] * t2 + tg[p][r];
                    }
                }
            }
            __syncthreads();
        }

        if (t < 72) {
            const int i = t / 3, c = t - (t / 3) * 3;
            tA[i][c] = tg[i][c] - (Rg[i][c * 3 + 0] * Jl[i][0]
                                 + Rg[i][c * 3 + 1] * Jl[i][1]
                                 + Rg[i][c * 3 + 2] * Jl[i][2]);
        }
        __syncthreads();

        if (t < 218) xs_ws[(size_t)b * 218 + t] = xs[t];
        if (t < 216) Rg_ws[(size_t)b * 216 + t] = ((const float*)Rg)[t];
        if (t < 72)  tA_ws[(size_t)b * 72 + t]  = ((const float*)tA)[t];
        return;
    }

    // ------------------------------ GEMM ----------------------------------
    const int ks = bid % KS2;
    const int nt = (bid / KS2) & 1;
    const int mt2 = bid / (KS2 * NT);
    const int w4 = t >> 6;
    const int lane15 = t & 15;
    const int kg = (t >> 4) & 3;
    const int kc0 = ks * KCP2;

    f32x4 acc[6][4];
    #pragma unroll
    for (int mf = 0; mf < 6; ++mf)
        #pragma unroll
        for (int nf = 0; nf < 4; ++nf) acc[mf][nf] = (f32x4){0.f, 0.f, 0.f, 0.f};

#define STAGE2(kc, buf) do { \
        _Pragma("unroll") \
        for (int q = 0; q < 3; ++q) { \
            if (t < 160) \
                GLOAD_LDS16((const char*)Apack + ((size_t)((3 * mt2 + q) * KC + (kc))) * 2560 + t * 16, \
                            smem + (buf) * 7680 + q * 2560 + (t >> 6) * 1024); \
        } \
        _Pragma("unroll") \
        for (int it = 0; it < 5; ++it) \
            GLOAD_LDS16((const char*)Bpack + ((size_t)(nt * KC + (kc))) * 20480 + (it * 256 + t) * 16, \
                        smem + 15360 + (buf) * 20480 + it * 4096 + (t >> 6) * 1024); \
    } while (0)

    STAGE2(kc0, 0);
    asm volatile("s_waitcnt vmcnt(0)" ::: "memory");
    __syncthreads();

    for (int i = 0; i < KCP2; ++i) {
        const int cur = i & 1;
        if (i < KCP2 - 1) STAGE2(kc0 + i + 1, cur ^ 1);

        short8 af[6];
        #pragma unroll
        for (int mf = 0; mf < 6; ++mf)
            af[mf] = *reinterpret_cast<const short8*>(
                smem + cur * 7680 + (mf * 16 + lane15) * 80 + kg * 16);
        #pragma unroll
        for (int nf = 0; nf < 4; ++nf) {
            const short8 bf = *reinterpret_cast<const short8*>(
                smem + 15360 + cur * 20480 + (w4 * 64 + nf * 16 + lane15) * 80 + kg * 16);
            #pragma unroll
            for (int mf = 0; mf < 6; ++mf)
                acc[mf][nf] = __builtin_amdgcn_mfma_f32_16x16x32_bf16(af[mf], bf, acc[mf][nf], 0, 0, 0);
        }
        if (i < KCP2 - 1) {
            asm volatile("s_waitcnt vmcnt(0)" ::: "memory");
            __syncthreads();
        }
    }
#undef STAGE2

    #pragma unroll
    for (int mf = 0; mf < 6; ++mf)
        #pragma unroll
        for (int nf = 0; nf < 4; ++nf) {
            const int m = mt2 * 96 + mf * 16 + kg * 4;
            const int col = nt * 256 + w4 * 64 + nf * 16 + lane15;
            #pragma unroll
            for (int reg = 0; reg < 4; ++reg)
                partials[((size_t)ks * MDIM + m + reg) * 512 + col] = acc[mf][nf][reg];
        }
}

// ---------------------------------------------------------------------------
// reduce: 336 blocks; sum 12 K-splits -> CCX rows 1..217. (Verified.)
// ---------------------------------------------------------------------------
__global__ __launch_bounds__(256) void reduce_k(
    const float* __restrict__ partials, float* __restrict__ CCX)
{
    const int idx = blockIdx.x * 256 + threadIdx.x;
    const int m = idx >> 7;
    const int col = (idx & 127) * 4;
    float4 s = {0.f, 0.f, 0.f, 0.f};
    #pragma unroll 6
    for (int ks = 0; ks < KS2; ++ks) {
        const float4 p = *reinterpret_cast<const float4*>(
            &partials[((size_t)ks * MDIM + m) * 512 + col]);
        s.x += p.x; s.y += p.y; s.z += p.z; s.w += p.w;
    }
    if (m < 657 && col < NCOLS) {
        const int r = m / 3, c = m - (m / 3) * 3;
        if (r != 0 && r != 218) {
            float sv[4] = {s.x, s.y, s.z, s.w};
            #pragma unroll
            for (int u = 0; u < 4; ++u)
                CCX[(size_t)r * RL + (col + u) * 3 + c] = sv[u];
        }
    }
}

// ---------------------------------------------------------------------------
// mgemm (ROUND-20 = exact round-16 version, the best-measured config at
// 81.3us total): async global_load_lds staging, serial vmcnt(0) per 32-row
// chunk, bgroup 8, 384 blocks (4 blocks/CU). r15 reg-staged=33.7us,
// r16 this=22.7us, r18 dbuf=24.8us, r19 dbuf+bg16@512t=27us.
// ---------------------------------------------------------------------------
__global__ __launch_bounds__(256) void mgemm(
    const float* __restrict__ xs_ws, const float* __restrict__ CCX,
    float* __restrict__ Ml)
{
    __shared__ float xsl[8 * 218];                    //  6976 B
    __shared__ __align__(16) float cl[32 * 228];      // 29184 B
    const int cg = blockIdx.x % 6;
    const int b0 = (blockIdx.x / 6) * 8;
    const int t = threadIdx.x;
    const int colbase = cg * 228;

    for (int i = t; i < 8 * 218; i += 256)
        xsl[i] = xs_ws[(size_t)b0 * 218 + i];

    float a8[8];
    #pragma unroll
    for (int bl = 0; bl < 8; ++bl) a8[bl] = 0.f;

    for (int rc = 0; rc < 218; rc += 32) {
        const int rn = (218 - rc < 32) ? (218 - rc) : 32;
        __syncthreads();               // prior compute reads (and xsl writes) done
        #pragma unroll
        for (int k = 0; k < 8; ++k) {
            const int i = t + k * 256;
            if (i < 1824) {            // 32 rows * 57 float4
                const int rl = i / 57;
                const int q = i - rl * 57;
                GLOAD_LDS16(CCX + (size_t)(rc + rl) * RL + colbase + q * 4,
                            (char*)cl + (size_t)i * 16);
            }
        }
        asm volatile("s_waitcnt vmcnt(0)" ::: "memory");
        __syncthreads();
        if (t < 228) {
            for (int rl = 0; rl < rn; ++rl) {
                const float cv = cl[rl * 228 + t];
                #pragma unroll
                for (int bl = 0; bl < 8; ++bl)
                    a8[bl] += xsl[bl * 218 + rc + rl] * cv;
            }
        }
    }

    if (t < 228) {
        #pragma unroll
        for (int bl = 0; bl < 8; ++bl)
            Ml[(size_t)(b0 + bl) * 1368 + colbase + t] = a8[bl];
    }
}

// ---------------------------------------------------------------------------
// joints: one block per b, 256 threads. (Verified.)
// ---------------------------------------------------------------------------
__global__ __launch_bounds__(256) void joints_k(
    const float* __restrict__ Ml, const float* __restrict__ Rg_ws,
    const float* __restrict__ tA_ws, const float* __restrict__ CCX,
    float* __restrict__ out)
{
    __shared__ float Mls[1368];
    __shared__ float Wj[1368];
    __shared__ float Rgs[216];
    __shared__ float tAs[72];
    const int b = blockIdx.x;
    const int t = threadIdx.x;

    for (int i = t; i < 342; i += 256) {
        reinterpret_cast<float4*>(Mls)[i] =
            reinterpret_cast<const float4*>(Ml + (size_t)b * 1368)[i];
        reinterpret_cast<float4*>(Wj)[i] =
            reinterpret_cast<const float4*>(CCX + (size_t)218 * RL)[i];
    }
    if (t < 216) Rgs[t] = Rg_ws[(size_t)b * 216 + t];
    if (t < 72)  tAs[t] = tA_ws[(size_t)b * 72 + t];
    __syncthreads();

    if (t < 57) {
        const int j = t / 3, c = t - (t / 3) * 3;
        float a = 0.f;
        #pragma unroll
        for (int i = 0; i < 24; ++i) {
            const int mb = (j * 24 + i) * 3;
            a += Rgs[i * 9 + c * 3 + 0] * Mls[mb + 0]
               + Rgs[i * 9 + c * 3 + 1] * Mls[mb + 1]
               + Rgs[i * 9 + c * 3 + 2] * Mls[mb + 2]
               + tAs[i * 3 + c] * Wj[mb];
        }
        out[b * 57 + t] = a;
    }
}

extern "C" void kernel_launch(void* const* d_in, const int* in_sizes, int n_in,
                              void* d_out, int out_size, void* d_ws, size_t ws_size,
                              hipStream_t stream) {
    const float* beta  = (const float*)d_in[0];
    const float* theta = (const float*)d_in[1];
    const float* vt    = (const float*)d_in[2];
    const float* sd    = (const float*)d_in[3];
    const float* pd    = (const float*)d_in[4];
    const float* Jreg  = (const float*)d_in[5];
    const float* jr    = (const float*)d_in[6];
    const float* w     = (const float*)d_in[7];
    float* outp = (float*)d_out;

    // ws layout (floats): CCX | partials(12) | Apack | Bpack | Jccx | xs | Rg | tA | vpart | Ml
    float* CCX = (float*)d_ws;
    float* partials = CCX + CCX_ELEMS;
    unsigned short* Apack = (unsigned short*)(partials + (size_t)KS2 * MDIM * 512);
    unsigned short* Bpack = Apack + (size_t)MT * KC * AIMG;
    float* Jccx  = (float*)(Bpack + (size_t)NT * KC * BIMG);
    float* xs_ws = Jccx + 792;
    float* Rg_ws = xs_ws + 512 * 218;
    float* tA_ws = Rg_ws + 512 * 216;
    float* vpart = tA_ws + 512 * 72;
    float* Ml    = vpart + (size_t)NVCH * VPROW;

    prep<<<491, 256, 0, stream>>>(vt, sd, pd, Jreg, jr, w, Apack, Bpack, CCX, Jccx, vpart);
    gemmchain<<<NGEMM + 8 + 512, 256, 0, stream>>>(Apack, Bpack, partials, vpart, CCX,
                                                   beta, theta, Jccx,
                                                   xs_ws, Rg_ws, tA_ws);
    reduce_k<<<336, 256, 0, stream>>>(partials, CCX);
    mgemm<<<384, 256, 0, stream>>>(xs_ws, CCX, Ml);
    joints_k<<<512, 256, 0, stream>>>(Ml, Rg_ws, tA_ws, CCX, outp);
}

// Round 21
// 70.104 us; speedup vs baseline: 1.2258x; 1.1583x over previous
//
#include <hip/hip_runtime.h>

#define VNUM 6890
#define SLEN 20670      // V*3
#define NJ 24
#define NJR 19
#define NB 10
#define NROWS 219
#define NCOLS 480
#define RL 1440         // NCOLS*3
#define CCX_ELEMS (NROWS * RL)
#define MLCOLS 1368

#define MDIM 672
#define MT   21         // 32-row A granules
#define NT   2
#define KC   216        // k-chunks of 32
#define AROW 40         // 32 data + 8 pad, bf16
#define AIMG (32 * AROW)
#define BIMG (256 * AROW)

// gemm96: 96-row tiles, 12 K-splits of 18 chunks
#define MT2 7
#define KS2 12
#define KCP2 18
#define NGEMM (MT2 * NT * KS2)   // 168

#define NVCH 27         // v-chunks of 256 for fp32 rows 0/218
#define VPROW 1824      // 456 cols * 4 vals per chunk

typedef short short8 __attribute__((ext_vector_type(8)));
typedef unsigned short u16x4 __attribute__((ext_vector_type(4)));
typedef float f32x4 __attribute__((ext_vector_type(4)));

#define GLOAD_LDS16(g, l) \
    __builtin_amdgcn_global_load_lds((const __attribute__((address_space(1))) void*)(g), \
                                     (__attribute__((address_space(3))) void*)(l), 16, 0, 0)

__constant__ int c_PAR[24]  = {0,0,0,0,1,2,3,4,5,6,7,8,9,9,9,12,13,14,16,17,18,19,20,21};
__constant__ int c_LOFF[10] = {0,1,4,7,10,15,18,20,22,24};

__device__ __forceinline__ unsigned short f2bf(float f) {
    union { float f; unsigned int u; } x; x.f = f;
    unsigned int r = x.u + 0x7fffu + ((x.u >> 16) & 1u);   // RNE
    return (unsigned short)(r >> 16);
}

// ---------------------------------------------------------------------------
// prep: packA(0..223) | packB(224..439) | vchunk(440..466) | Jcols(467..490).
// (Verified rounds 13-20, byte-identical.)
// ---------------------------------------------------------------------------
__global__ __launch_bounds__(256) void prep(
    const float* __restrict__ vt, const float* __restrict__ sd,
    const float* __restrict__ pd, const float* __restrict__ Jreg,
    const float* __restrict__ jr, const float* __restrict__ w,
    unsigned short* __restrict__ Apack, unsigned short* __restrict__ Bpack,
    float* __restrict__ CCX, float* __restrict__ Jccx,
    float* __restrict__ vpart)
{
    __shared__ float jrl_b[256 * NJR];   // 19456 B
    __shared__ float wl_b[256 * NJ];     // 24576 B
    __shared__ float vtl[256 * 3];       //  3072 B

    const int bid = blockIdx.x;
    const int t = threadIdx.x;

    if (bid < 224) {
        const int r = bid;
        const float* src = (r == 0) ? vt
                         : (r <= 10 ? sd + (size_t)(r - 1) * SLEN
                         : (r <= 217 ? pd + (size_t)(r - 11) * SLEN : nullptr));
        for (int g = t; g < 1728; g += 256) {
            const int v = 4 * g;
            float lv[12];
            if (r <= 217) {
                if (3 * v + 12 <= SLEN) {
                    const float4 a = *reinterpret_cast<const float4*>(src + 3 * v);
                    const float4 b4 = *reinterpret_cast<const float4*>(src + 3 * v + 4);
                    const float4 c4 = *reinterpret_cast<const float4*>(src + 3 * v + 8);
                    lv[0]=a.x; lv[1]=a.y; lv[2]=a.z; lv[3]=a.w;
                    lv[4]=b4.x; lv[5]=b4.y; lv[6]=b4.z; lv[7]=b4.w;
                    lv[8]=c4.x; lv[9]=c4.y; lv[10]=c4.z; lv[11]=c4.w;
                } else {
                    #pragma unroll
                    for (int l = 0; l < 12; ++l) {
                        const int idx = 3 * v + l;
                        lv[l] = (idx < SLEN) ? src[idx] : 0.f;
                    }
                }
            } else if (r == 218) {
                #pragma unroll
                for (int l = 0; l < 12; ++l) lv[l] = (v + l / 3 < VNUM) ? 1.f : 0.f;
            } else {
                #pragma unroll
                for (int l = 0; l < 12; ++l) lv[l] = 0.f;
            }
            const int kc = v >> 5, kk = v & 31;
            #pragma unroll
            for (int c = 0; c < 3; ++c) {
                const int m = 3 * r + c;
                const int mt = m >> 5, mrow = m & 31;
                u16x4 s = {f2bf(lv[c]), f2bf(lv[3 + c]), f2bf(lv[6 + c]), f2bf(lv[9 + c])};
                *reinterpret_cast<u16x4*>(
                    &Apack[((size_t)(mt * KC + kc) * 32 + mrow) * AROW + kk]) = s;
            }
        }
    } else if (bid < 440) {
        const int kc = bid - 224;
        const int v0 = kc * 32;
        float* jrl = jrl_b;
        float* wl  = jrl_b + 32 * NJR;
        float* Jl2 = wl + 32 * NJ;
        for (int i = t; i < 32 * NJR; i += 256) {
            const int g = v0 * NJR + i;
            jrl[i] = (g < VNUM * NJR) ? jr[g] : 0.f;
        }
        for (int i = t; i < 32 * NJ; i += 256) {
            const int g = v0 * NJ + i;
            wl[i]  = (g < VNUM * NJ) ? w[g] : 0.f;
            Jl2[i] = (g < VNUM * NJ) ? Jreg[g] : 0.f;
        }
        __syncthreads();
        #pragma unroll
        for (int nt = 0; nt < NT; ++nt) {
            const int col = nt * 256 + t;
            const int j = col / 24, i = col - j * 24;
            short8 ov[4];
            #pragma unroll
            for (int kk = 0; kk < 32; ++kk) {
                float val = 0.f;
                if (v0 + kk < VNUM) {
                    if (col < 456)      val = jrl[kk * NJR + j] * wl[kk * NJ + i];
                    else if (col < 480) val = Jl2[kk * NJ + (col - 456)];
                }
                ov[kk >> 3][kk & 7] = (short)f2bf(val);
            }
            unsigned short* dst = Bpack + ((size_t)(nt * KC + kc) * 256 + t) * AROW;
            #pragma unroll
            for (int q = 0; q < 4; ++q)
                *reinterpret_cast<short8*>(dst + 8 * q) = ov[q];
        }
    } else if (bid < 467) {
        const int ch = bid - 440;
        const int v0 = ch * 256;
        for (int i = t; i < 256 * NJR; i += 256) {
            const int g = v0 * NJR + i;
            jrl_b[i] = (g < VNUM * NJR) ? jr[g] : 0.f;
        }
        for (int i = t; i < 256 * NJ; i += 256) {
            const int g = v0 * NJ + i;
            wl_b[i] = (g < VNUM * NJ) ? w[g] : 0.f;
        }
        for (int i = t; i < 256 * 3; i += 256) {
            const int g = v0 * 3 + i;
            vtl[i] = (g < VNUM * 3) ? vt[g] : 0.f;
        }
        __syncthreads();
        if (t < 228) {
            #pragma unroll
            for (int cc2 = 0; cc2 < 2; ++cc2) {
                const int col = t + cc2 * 228;
                const int j = col / 24, i2 = col - j * 24;
                float s0 = 0.f, s1 = 0.f, s2 = 0.f, s3 = 0.f;
                #pragma unroll 4
                for (int v = 0; v < 256; ++v) {
                    const float coef = jrl_b[v * NJR + j] * wl_b[v * NJ + i2];
                    s0 += coef * vtl[v * 3 + 0];
                    s1 += coef * vtl[v * 3 + 1];
                    s2 += coef * vtl[v * 3 + 2];
                    s3 += coef;
                }
                float4 pv = {s0, s1, s2, s3};
                *reinterpret_cast<float4*>(&vpart[(size_t)ch * VPROW + col * 4]) = pv;
            }
        }
    } else {
        const int jj = bid - 467;        // 0..23
        const int col = 456 + jj;
        float ja[34];
        #pragma unroll
        for (int k = 0; k < 34; ++k) ja[k] = 0.f;
        for (int v = t; v < VNUM; v += 256) {
            const float coef = Jreg[v * NJ + jj];
            ja[33] += coef;
            #pragma unroll
            for (int c = 0; c < 3; ++c) ja[c] += coef * vt[3 * v + c];
            #pragma unroll
            for (int r = 1; r <= 10; ++r)
                #pragma unroll
                for (int c = 0; c < 3; ++c)
                    ja[r * 3 + c] += coef * sd[(size_t)(r - 1) * SLEN + 3 * v + c];
        }
        float* red = jrl_b;              // [4][34]
        #pragma unroll
        for (int k = 0; k < 34; ++k) {
            float vv = ja[k];
            #pragma unroll
            for (int off = 32; off; off >>= 1) vv += __shfl_down(vv, off);
            if ((t & 63) == 0) red[(t >> 6) * 34 + k] = vv;
        }
        __syncthreads();
        if (t == 0) {
            #pragma unroll
            for (int k = 0; k < 34; ++k) {
                const float s = red[0 * 34 + k] + red[1 * 34 + k]
                              + red[2 * 34 + k] + red[3 * 34 + k];
                if (k < 33) {
                    const int r = k / 3, c = k - (k / 3) * 3;
                    Jccx[r * 72 + jj * 3 + c] = s;
                    if (r == 0) CCX[col * 3 + c] = s;
                } else {
                    CCX[(size_t)218 * RL + col * 3 + 0] = s;
                    CCX[(size_t)218 * RL + col * 3 + 1] = s;
                    CCX[(size_t)218 * RL + col * 3 + 2] = s;
                }
            }
        }
    }
}

// ---------------------------------------------------------------------------
// gemmchain: bid<168 GEMM | bid 168..175 vred | bid 176..687 chain.
// ROUND-21 CHANGE (chain only): instead of xs_ws fp32, write Xbpack bf16 in
// Apack-style images [((bt*7+kc)*32+brow)*40+kk]: k=0..216 <- xs[k+1];
// k=217..223 ZEROED (A-side zero pad neutralizes poisoned B pad).
// ---------------------------------------------------------------------------
__global__ __launch_bounds__(256) void gemmchain(
    const unsigned short* __restrict__ Apack,
    const unsigned short* __restrict__ Bpack,
    float* __restrict__ partials,
    const float* __restrict__ vpart, float* __restrict__ CCX,
    const float* __restrict__ beta, const float* __restrict__ theta,
    const float* __restrict__ Jccx,
    unsigned short* __restrict__ Xbpack,
    float* __restrict__ Rg_ws, float* __restrict__ tA_ws)
{
    __shared__ __align__(16) char smem[2 * 7680 + 2 * 20480];   // 56320
    const int bid = blockIdx.x;
    const int t = threadIdx.x;

    if (bid >= NGEMM) {
        if (bid < NGEMM + 8) {
            const int tid = (bid - NGEMM) * 256 + t;
            if (tid < 456 * 4) {
                float s = 0.f;
                #pragma unroll 9
                for (int ch = 0; ch < NVCH; ++ch)
                    s += vpart[(size_t)ch * VPROW + tid];
                const int col = tid >> 2, q = tid & 3;
                if (q < 3) {
                    CCX[col * 3 + q] = s;
                } else {
                    CCX[(size_t)218 * RL + col * 3 + 0] = s;
                    CCX[(size_t)218 * RL + col * 3 + 1] = s;
                    CCX[(size_t)218 * RL + col * 3 + 2] = s;
                }
            }
            return;
        }
        float* F = (float*)smem;
        float* xs = F;                       // 218
        float (*Rl)[9] = (float(*)[9])(F + 224);
        float (*Rg)[9] = (float(*)[9])(F + 440);
        float (*tg)[3] = (float(*)[3])(F + 656);
        float (*tA)[3] = (float(*)[3])(F + 728);
        float (*Jl)[3] = (float(*)[3])(F + 800);
        const int b = bid - (NGEMM + 8);

        if (t < 24) {
            const int i = t;
            const float tx = theta[b * 72 + 3 * i + 0];
            const float ty = theta[b * 72 + 3 * i + 1];
            const float tz = theta[b * 72 + 3 * i + 2];
            const float ax = tx + 1e-8f, ay = ty + 1e-8f, az = tz + 1e-8f;
            const float angle = sqrtf(ax * ax + ay * ay + az * az);
            const float half = 0.5f * angle;
            const float sh = sinf(half), chh = cosf(half);
            const float inv = 1.f / angle;
            float qw = chh, qx = sh * tx * inv, qy = sh * ty * inv, qz = sh * tz * inv;
            const float rn = 1.f / sqrtf(qw * qw + qx * qx + qy * qy + qz * qz);
            qw *= rn; qx *= rn; qy *= rn; qz *= rn;
            float R[9];
            R[0] = 1.f - 2.f * (qy * qy + qz * qz);
            R[1] = 2.f * (qx * qy - qw * qz);
            R[2] = 2.f * (qx * qz + qw * qy);
            R[3] = 2.f * (qx * qy + qw * qz);
            R[4] = 1.f - 2.f * (qx * qx + qz * qz);
            R[5] = 2.f * (qy * qz - qw * qx);
            R[6] = 2.f * (qx * qz - qw * qy);
            R[7] = 2.f * (qy * qz + qw * qx);
            R[8] = 1.f - 2.f * (qx * qx + qy * qy);
            #pragma unroll
            for (int e = 0; e < 9; ++e) Rl[i][e] = R[e];
            if (i >= 1) {
                #pragma unroll
                for (int e = 0; e < 9; ++e)
                    xs[11 + (i - 1) * 9 + e] = R[e] - ((e == 0 || e == 4 || e == 8) ? 1.f : 0.f);
            }
        } else if (t == 24) {
            xs[0] = 1.f;
        } else if (t >= 25 && t < 35) {
            xs[t - 24] = beta[b * NB + (t - 25)];
        }
        __syncthreads();

        if (t < 72) {
            const int jj = t / 3, c = t - (t / 3) * 3;
            float a = 0.f;
            #pragma unroll
            for (int r = 0; r <= 10; ++r)
                a += xs[r] * Jccx[r * 72 + jj * 3 + c];
            Jl[jj][c] = a;
        }
        __syncthreads();

        for (int lv = 0; lv < 9; ++lv) {
            const int beg = c_LOFF[lv];
            const int cnt = c_LOFF[lv + 1] - beg;
            if (t < cnt * 12) {
                const int li = t / 12, e = t - li * 12;
                const int j = beg + li;
                const int r = e >> 2, cc = e & 3;
                if (lv == 0) {
                    if (cc < 3) Rg[0][r * 3 + cc] = Rl[0][r * 3 + cc] * ((cc == 0) ? 1.f : -1.f);
                    else        tg[0][r] = Jl[0][r];
                } else {
                    const int p = c_PAR[j];
                    if (cc < 3) {
                        Rg[j][r * 3 + cc] = Rg[p][r * 3 + 0] * Rl[j][0 + cc]
                                          + Rg[p][r * 3 + 1] * Rl[j][3 + cc]
                                          + Rg[p][r * 3 + 2] * Rl[j][6 + cc];
                    } else {
                        const float t0 = Jl[j][0] - Jl[p][0];
                        const float t1 = Jl[j][1] - Jl[p][1];
                        const float t2 = Jl[j][2] - Jl[p][2];
                        tg[j][r] = Rg[p][r * 3 + 0] * t0 + Rg[p][r * 3 + 1] * t1
                                 + Rg[p][r * 3 + 2] * t2 + tg[p][r];
                    }
                }
            }
            __syncthreads();
        }

        if (t < 72) {
            const int i = t / 3, c = t - (t / 3) * 3;
            tA[i][c] = tg[i][c] - (Rg[i][c * 3 + 0] * Jl[i][0]
                                 + Rg[i][c * 3 + 1] * Jl[i][1]
                                 + Rg[i][c * 3 + 2] * Jl[i][2]);
        }
        __syncthreads();

        if (t < 224) {                   // k = t: 0..216 real, 217..223 ZERO pad
            const unsigned short hv = (t < 217) ? f2bf(xs[t + 1]) : (unsigned short)0;
            const int bt = b >> 5, brow = b & 31, kc = t >> 5, kk = t & 31;
            Xbpack[((size_t)(bt * 7 + kc) * 32 + brow) * 40 + kk] = hv;
        }
        if (t < 216) Rg_ws[(size_t)b * 216 + t] = ((const float*)Rg)[t];
        if (t < 72)  tA_ws[(size_t)b * 72 + t]  = ((const float*)tA)[t];
        return;
    }

    // ------------------------------ GEMM ----------------------------------
    const int ks = bid % KS2;
    const int nt = (bid / KS2) & 1;
    const int mt2 = bid / (KS2 * NT);
    const int w4 = t >> 6;
    const int lane15 = t & 15;
    const int kg = (t >> 4) & 3;
    const int kc0 = ks * KCP2;

    f32x4 acc[6][4];
    #pragma unroll
    for (int mf = 0; mf < 6; ++mf)
        #pragma unroll
        for (int nf = 0; nf < 4; ++nf) acc[mf][nf] = (f32x4){0.f, 0.f, 0.f, 0.f};

#define STAGE2(kc, buf) do { \
        _Pragma("unroll") \
        for (int q = 0; q < 3; ++q) { \
            if (t < 160) \
                GLOAD_LDS16((const char*)Apack + ((size_t)((3 * mt2 + q) * KC + (kc))) * 2560 + t * 16, \
                            smem + (buf) * 7680 + q * 2560 + (t >> 6) * 1024); \
        } \
        _Pragma("unroll") \
        for (int it = 0; it < 5; ++it) \
            GLOAD_LDS16((const char*)Bpack + ((size_t)(nt * KC + (kc))) * 20480 + (it * 256 + t) * 16, \
                        smem + 15360 + (buf) * 20480 + it * 4096 + (t >> 6) * 1024); \
    } while (0)

    STAGE2(kc0, 0);
    asm volatile("s_waitcnt vmcnt(0)" ::: "memory");
    __syncthreads();

    for (int i = 0; i < KCP2; ++i) {
        const int cur = i & 1;
        if (i < KCP2 - 1) STAGE2(kc0 + i + 1, cur ^ 1);

        short8 af[6];
        #pragma unroll
        for (int mf = 0; mf < 6; ++mf)
            af[mf] = *reinterpret_cast<const short8*>(
                smem + cur * 7680 + (mf * 16 + lane15) * 80 + kg * 16);
        #pragma unroll
        for (int nf = 0; nf < 4; ++nf) {
            const short8 bf = *reinterpret_cast<const short8*>(
                smem + 15360 + cur * 20480 + (w4 * 64 + nf * 16 + lane15) * 80 + kg * 16);
            #pragma unroll
            for (int mf = 0; mf < 6; ++mf)
                acc[mf][nf] = __builtin_amdgcn_mfma_f32_16x16x32_bf16(af[mf], bf, acc[mf][nf], 0, 0, 0);
        }
        if (i < KCP2 - 1) {
            asm volatile("s_waitcnt vmcnt(0)" ::: "memory");
            __syncthreads();
        }
    }
#undef STAGE2

    #pragma unroll
    for (int mf = 0; mf < 6; ++mf)
        #pragma unroll
        for (int nf = 0; nf < 4; ++nf) {
            const int m = mt2 * 96 + mf * 16 + kg * 4;
            const int col = nt * 256 + w4 * 64 + nf * 16 + lane15;
            #pragma unroll
            for (int reg = 0; reg < 4; ++reg)
                partials[((size_t)ks * MDIM + m + reg) * 512 + col] = acc[mf][nf][reg];
        }
}

// ---------------------------------------------------------------------------
// reduce: 336 blocks; sum 12 K-splits -> CCX rows 1..217 fp32 AND Cbpack bf16
// (B operand for mgemm_mfma): [((ct*7+kc)*256+colrow)*40+kk], k=r-1,
// colIdx=(col+u)*3+c < 1368.
// ---------------------------------------------------------------------------
__global__ __launch_bounds__(256) void reduce_k(
    const float* __restrict__ partials, float* __restrict__ CCX,
    unsigned short* __restrict__ Cbpack)
{
    const int idx = blockIdx.x * 256 + threadIdx.x;
    const int m = idx >> 7;
    const int col = (idx & 127) * 4;
    float4 s = {0.f, 0.f, 0.f, 0.f};
    #pragma unroll 6
    for (int ks = 0; ks < KS2; ++ks) {
        const float4 p = *reinterpret_cast<const float4*>(
            &partials[((size_t)ks * MDIM + m) * 512 + col]);
        s.x += p.x; s.y += p.y; s.z += p.z; s.w += p.w;
    }
    if (m < 657 && col < NCOLS) {
        const int r = m / 3, c = m - (m / 3) * 3;
        if (r != 0 && r != 218) {
            float sv[4] = {s.x, s.y, s.z, s.w};
            #pragma unroll
            for (int u = 0; u < 4; ++u)
                CCX[(size_t)r * RL + (col + u) * 3 + c] = sv[u];
            const int k = r - 1;                  // 0..216
            const int kc2 = k >> 5, kk = k & 31;
            #pragma unroll
            for (int u = 0; u < 4; ++u) {
                const int colIdx = (col + u) * 3 + c;
                if (colIdx < MLCOLS) {
                    const int ct2 = colIdx >> 8, colrow = colIdx & 255;
                    Cbpack[((size_t)(ct2 * 7 + kc2) * 256 + colrow) * 40 + kk] = f2bf(sv[u]);
                }
            }
        }
    }
}

// ---------------------------------------------------------------------------
// mgemm_mfma (ROUND-21): Ml[b][col] = CCX[0][col] + sum_k Xb[b][k]*Cb[k][col].
// 96 blocks = 16 bt x 6 ct; tile 32b x 256col, 4 waves x 8 frags; K=224 in 7
// double-buffered chunks. Structure/addressing copied from the round-4
// verified gemm_mfma. Cols >= 1368 compute on poisoned B (harmless bf16
// values, A pad is zero) and are never written.
// ---------------------------------------------------------------------------
__global__ __launch_bounds__(256) void mgemm_mfma(
    const unsigned short* __restrict__ Xbpack,
    const unsigned short* __restrict__ Cbpack,
    const float* __restrict__ CCX,
    float* __restrict__ Ml)
{
    __shared__ __align__(16) char smem[2 * 2560 + 2 * 20480];   // 46080
    const int AOFF[2] = {0, 2560};
    const int BOFF[2] = {5120, 5120 + 20480};
    const int bid = blockIdx.x;
    const int ct = bid % 6;
    const int bt = bid / 6;
    const int t = threadIdx.x;
    const int w = t >> 6;
    const int lane15 = t & 15;
    const int kg = (t >> 4) & 3;
    const int mrow0 = (w & 1) * 16;
    const int ncol0 = (w >> 1) * 128;

#define MSTG(kc, buf) do { \
        const char* ga = (const char*)Xbpack + ((size_t)(bt * 7 + (kc))) * 2560; \
        const char* gb = (const char*)Cbpack + ((size_t)(ct * 7 + (kc))) * 20480; \
        if (t < 160) GLOAD_LDS16(ga + t * 16, smem + AOFF[buf] + (t >> 6) * 1024); \
        _Pragma("unroll") \
        for (int it = 0; it < 5; ++it) \
            GLOAD_LDS16(gb + (it * 256 + t) * 16, smem + BOFF[buf] + it * 4096 + (t >> 6) * 1024); \
    } while (0)

    f32x4 acc[8];
    #pragma unroll
    for (int f = 0; f < 8; ++f) acc[f] = (f32x4){0.f, 0.f, 0.f, 0.f};

    MSTG(0, 0);
    asm volatile("s_waitcnt vmcnt(0)" ::: "memory");
    __syncthreads();

    for (int i = 0; i < 7; ++i) {
        const int cur = i & 1;
        if (i < 6) MSTG(i + 1, cur ^ 1);

        const short8 af = *reinterpret_cast<const short8*>(
            smem + AOFF[cur] + (mrow0 + lane15) * 80 + kg * 16);
        #pragma unroll
        for (int f = 0; f < 8; ++f) {
            const short8 bf = *reinterpret_cast<const short8*>(
                smem + BOFF[cur] + (ncol0 + f * 16 + lane15) * 80 + kg * 16);
            acc[f] = __builtin_amdgcn_mfma_f32_16x16x32_bf16(af, bf, acc[f], 0, 0, 0);
        }
        if (i < 6) {
            asm volatile("s_waitcnt vmcnt(0)" ::: "memory");
            __syncthreads();
        }
    }
#undef MSTG

    #pragma unroll
    for (int f = 0; f < 8; ++f) {
        const int colp = ct * 256 + ncol0 + f * 16 + lane15;
        if (colp < MLCOLS) {
            const float base = CCX[colp];          // row 0 (fp32 exact, xs[0]=1)
            const int bb = bt * 32 + mrow0 + kg * 4;
            #pragma unroll
            for (int reg = 0; reg < 4; ++reg)
                Ml[(size_t)(bb + reg) * MLCOLS + colp] = acc[f][reg] + base;
        }
    }
}

// ---------------------------------------------------------------------------
// joints: one block per b, 256 threads. (Verified.)
// ---------------------------------------------------------------------------
__global__ __launch_bounds__(256) void joints_k(
    const float* __restrict__ Ml, const float* __restrict__ Rg_ws,
    const float* __restrict__ tA_ws, const float* __restrict__ CCX,
    float* __restrict__ out)
{
    __shared__ float Mls[1368];
    __shared__ float Wj[1368];
    __shared__ float Rgs[216];
    __shared__ float tAs[72];
    const int b = blockIdx.x;
    const int t = threadIdx.x;

    for (int i = t; i < 342; i += 256) {
        reinterpret_cast<float4*>(Mls)[i] =
            reinterpret_cast<const float4*>(Ml + (size_t)b * 1368)[i];
        reinterpret_cast<float4*>(Wj)[i] =
            reinterpret_cast<const float4*>(CCX + (size_t)218 * RL)[i];
    }
    if (t < 216) Rgs[t] = Rg_ws[(size_t)b * 216 + t];
    if (t < 72)  tAs[t] = tA_ws[(size_t)b * 72 + t];
    __syncthreads();

    if (t < 57) {
        const int j = t / 3, c = t - (t / 3) * 3;
        float a = 0.f;
        #pragma unroll
        for (int i = 0; i < 24; ++i) {
            const int mb = (j * 24 + i) * 3;
            a += Rgs[i * 9 + c * 3 + 0] * Mls[mb + 0]
               + Rgs[i * 9 + c * 3 + 1] * Mls[mb + 1]
               + Rgs[i * 9 + c * 3 + 2] * Mls[mb + 2]
               + tAs[i * 3 + c] * Wj[mb];
        }
        out[b * 57 + t] = a;
    }
}

extern "C" void kernel_launch(void* const* d_in, const int* in_sizes, int n_in,
                              void* d_out, int out_size, void* d_ws, size_t ws_size,
                              hipStream_t stream) {
    const float* beta  = (const float*)d_in[0];
    const float* theta = (const float*)d_in[1];
    const float* vt    = (const float*)d_in[2];
    const float* sd    = (const float*)d_in[3];
    const float* pd    = (const float*)d_in[4];
    const float* Jreg  = (const float*)d_in[5];
    const float* jr    = (const float*)d_in[6];
    const float* w     = (const float*)d_in[7];
    float* outp = (float*)d_out;

    // ws layout (floats): CCX | partials(12) | Apack | Bpack | Jccx | Rg | tA |
    //                     vpart | Ml | Xbpack | Cbpack
    float* CCX = (float*)d_ws;
    float* partials = CCX + CCX_ELEMS;
    unsigned short* Apack = (unsigned short*)(partials + (size_t)KS2 * MDIM * 512);
    unsigned short* Bpack = Apack + (size_t)MT * KC * AIMG;
    float* Jccx  = (float*)(Bpack + (size_t)NT * KC * BIMG);
    float* Rg_ws = Jccx + 792;
    float* tA_ws = Rg_ws + 512 * 216;
    float* vpart = tA_ws + 512 * 72;
    float* Ml    = vpart + (size_t)NVCH * VPROW;
    unsigned short* Xbpack = (unsigned short*)(Ml + (size_t)512 * MLCOLS);
    unsigned short* Cbpack = Xbpack + (size_t)16 * 7 * 32 * 40;

    prep<<<491, 256, 0, stream>>>(vt, sd, pd, Jreg, jr, w, Apack, Bpack, CCX, Jccx, vpart);
    gemmchain<<<NGEMM + 8 + 512, 256, 0, stream>>>(Apack, Bpack, partials, vpart, CCX,
                                                   beta, theta, Jccx,
                                                   Xbpack, Rg_ws, tA_ws);
    reduce_k<<<336, 256, 0, stream>>>(partials, CCX, Cbpack);
    mgemm_mfma<<<96, 256, 0, stream>>>(Xbpack, Cbpack, CCX, Ml);
    joints_k<<<512, 256, 0, stream>>>(Ml, Rg_ws, tA_ws, CCX, outp);
}

// Round 22
// 67.196 us; speedup vs baseline: 1.2788x; 1.0433x over previous
//
#include <hip/hip_runtime.h>

#define VNUM 6890
#define SLEN 20670      // V*3
#define NJ 24
#define NJR 19
#define NB 10
#define NROWS 219
#define NCOLS 480
#define RL 1440         // NCOLS*3
#define CCX_ELEMS (NROWS * RL)
#define MLCOLS 1368

#define MDIM 672
#define MT   21         // 32-row A granules
#define NT   2
#define KC   216        // k-chunks of 32
#define AROW 40         // 32 data + 8 pad, bf16
#define AIMG (32 * AROW)
#define BIMG (256 * AROW)

// gemm96: 96-row tiles, 12 K-splits of 18 chunks
#define MT2 7
#define KS2 12
#define KCP2 18
#define NGEMM (MT2 * NT * KS2)   // 168

#define NVCH 27         // v-chunks of 256 for fp32 rows 0/218
#define VPROW 1824      // 456 cols * 4 vals per chunk

typedef short short8 __attribute__((ext_vector_type(8)));
typedef unsigned short u16x4 __attribute__((ext_vector_type(4)));
typedef float f32x4 __attribute__((ext_vector_type(4)));

#define GLOAD_LDS16(g, l) \
    __builtin_amdgcn_global_load_lds((const __attribute__((address_space(1))) void*)(g), \
                                     (__attribute__((address_space(3))) void*)(l), 16, 0, 0)

__constant__ int c_PAR[24]  = {0,0,0,0,1,2,3,4,5,6,7,8,9,9,9,12,13,14,16,17,18,19,20,21};
__constant__ int c_LOFF[10] = {0,1,4,7,10,15,18,20,22,24};

__device__ __forceinline__ unsigned short f2bf(float f) {
    union { float f; unsigned int u; } x; x.f = f;
    unsigned int r = x.u + 0x7fffu + ((x.u >> 16) & 1u);   // RNE
    return (unsigned short)(r >> 16);
}

// ---------------------------------------------------------------------------
// prep: packA(0..223) | packB(224..439) | vchunk(440..466) | Jcols(467..490).
// (Verified rounds 13-21, byte-identical.)
// ---------------------------------------------------------------------------
__global__ __launch_bounds__(256) void prep(
    const float* __restrict__ vt, const float* __restrict__ sd,
    const float* __restrict__ pd, const float* __restrict__ Jreg,
    const float* __restrict__ jr, const float* __restrict__ w,
    unsigned short* __restrict__ Apack, unsigned short* __restrict__ Bpack,
    float* __restrict__ CCX, float* __restrict__ Jccx,
    float* __restrict__ vpart)
{
    __shared__ float jrl_b[256 * NJR];   // 19456 B
    __shared__ float wl_b[256 * NJ];     // 24576 B
    __shared__ float vtl[256 * 3];       //  3072 B

    const int bid = blockIdx.x;
    const int t = threadIdx.x;

    if (bid < 224) {
        const int r = bid;
        const float* src = (r == 0) ? vt
                         : (r <= 10 ? sd + (size_t)(r - 1) * SLEN
                         : (r <= 217 ? pd + (size_t)(r - 11) * SLEN : nullptr));
        for (int g = t; g < 1728; g += 256) {
            const int v = 4 * g;
            float lv[12];
            if (r <= 217) {
                if (3 * v + 12 <= SLEN) {
                    const float4 a = *reinterpret_cast<const float4*>(src + 3 * v);
                    const float4 b4 = *reinterpret_cast<const float4*>(src + 3 * v + 4);
                    const float4 c4 = *reinterpret_cast<const float4*>(src + 3 * v + 8);
                    lv[0]=a.x; lv[1]=a.y; lv[2]=a.z; lv[3]=a.w;
                    lv[4]=b4.x; lv[5]=b4.y; lv[6]=b4.z; lv[7]=b4.w;
                    lv[8]=c4.x; lv[9]=c4.y; lv[10]=c4.z; lv[11]=c4.w;
                } else {
                    #pragma unroll
                    for (int l = 0; l < 12; ++l) {
                        const int idx = 3 * v + l;
                        lv[l] = (idx < SLEN) ? src[idx] : 0.f;
                    }
                }
            } else if (r == 218) {
                #pragma unroll
                for (int l = 0; l < 12; ++l) lv[l] = (v + l / 3 < VNUM) ? 1.f : 0.f;
            } else {
                #pragma unroll
                for (int l = 0; l < 12; ++l) lv[l] = 0.f;
            }
            const int kc = v >> 5, kk = v & 31;
            #pragma unroll
            for (int c = 0; c < 3; ++c) {
                const int m = 3 * r + c;
                const int mt = m >> 5, mrow = m & 31;
                u16x4 s = {f2bf(lv[c]), f2bf(lv[3 + c]), f2bf(lv[6 + c]), f2bf(lv[9 + c])};
                *reinterpret_cast<u16x4*>(
                    &Apack[((size_t)(mt * KC + kc) * 32 + mrow) * AROW + kk]) = s;
            }
        }
    } else if (bid < 440) {
        const int kc = bid - 224;
        const int v0 = kc * 32;
        float* jrl = jrl_b;
        float* wl  = jrl_b + 32 * NJR;
        float* Jl2 = wl + 32 * NJ;
        for (int i = t; i < 32 * NJR; i += 256) {
            const int g = v0 * NJR + i;
            jrl[i] = (g < VNUM * NJR) ? jr[g] : 0.f;
        }
        for (int i = t; i < 32 * NJ; i += 256) {
            const int g = v0 * NJ + i;
            wl[i]  = (g < VNUM * NJ) ? w[g] : 0.f;
            Jl2[i] = (g < VNUM * NJ) ? Jreg[g] : 0.f;
        }
        __syncthreads();
        #pragma unroll
        for (int nt = 0; nt < NT; ++nt) {
            const int col = nt * 256 + t;
            const int j = col / 24, i = col - j * 24;
            short8 ov[4];
            #pragma unroll
            for (int kk = 0; kk < 32; ++kk) {
                float val = 0.f;
                if (v0 + kk < VNUM) {
                    if (col < 456)      val = jrl[kk * NJR + j] * wl[kk * NJ + i];
                    else if (col < 480) val = Jl2[kk * NJ + (col - 456)];
                }
                ov[kk >> 3][kk & 7] = (short)f2bf(val);
            }
            unsigned short* dst = Bpack + ((size_t)(nt * KC + kc) * 256 + t) * AROW;
            #pragma unroll
            for (int q = 0; q < 4; ++q)
                *reinterpret_cast<short8*>(dst + 8 * q) = ov[q];
        }
    } else if (bid < 467) {
        const int ch = bid - 440;
        const int v0 = ch * 256;
        for (int i = t; i < 256 * NJR; i += 256) {
            const int g = v0 * NJR + i;
            jrl_b[i] = (g < VNUM * NJR) ? jr[g] : 0.f;
        }
        for (int i = t; i < 256 * NJ; i += 256) {
            const int g = v0 * NJ + i;
            wl_b[i] = (g < VNUM * NJ) ? w[g] : 0.f;
        }
        for (int i = t; i < 256 * 3; i += 256) {
            const int g = v0 * 3 + i;
            vtl[i] = (g < VNUM * 3) ? vt[g] : 0.f;
        }
        __syncthreads();
        if (t < 228) {
            #pragma unroll
            for (int cc2 = 0; cc2 < 2; ++cc2) {
                const int col = t + cc2 * 228;
                const int j = col / 24, i2 = col - j * 24;
                float s0 = 0.f, s1 = 0.f, s2 = 0.f, s3 = 0.f;
                #pragma unroll 4
                for (int v = 0; v < 256; ++v) {
                    const float coef = jrl_b[v * NJR + j] * wl_b[v * NJ + i2];
                    s0 += coef * vtl[v * 3 + 0];
                    s1 += coef * vtl[v * 3 + 1];
                    s2 += coef * vtl[v * 3 + 2];
                    s3 += coef;
                }
                float4 pv = {s0, s1, s2, s3};
                *reinterpret_cast<float4*>(&vpart[(size_t)ch * VPROW + col * 4]) = pv;
            }
        }
    } else {
        const int jj = bid - 467;        // 0..23
        const int col = 456 + jj;
        float ja[34];
        #pragma unroll
        for (int k = 0; k < 34; ++k) ja[k] = 0.f;
        for (int v = t; v < VNUM; v += 256) {
            const float coef = Jreg[v * NJ + jj];
            ja[33] += coef;
            #pragma unroll
            for (int c = 0; c < 3; ++c) ja[c] += coef * vt[3 * v + c];
            #pragma unroll
            for (int r = 1; r <= 10; ++r)
                #pragma unroll
                for (int c = 0; c < 3; ++c)
                    ja[r * 3 + c] += coef * sd[(size_t)(r - 1) * SLEN + 3 * v + c];
        }
        float* red = jrl_b;              // [4][34]
        #pragma unroll
        for (int k = 0; k < 34; ++k) {
            float vv = ja[k];
            #pragma unroll
            for (int off = 32; off; off >>= 1) vv += __shfl_down(vv, off);
            if ((t & 63) == 0) red[(t >> 6) * 34 + k] = vv;
        }
        __syncthreads();
        if (t == 0) {
            #pragma unroll
            for (int k = 0; k < 34; ++k) {
                const float s = red[0 * 34 + k] + red[1 * 34 + k]
                              + red[2 * 34 + k] + red[3 * 34 + k];
                if (k < 33) {
                    const int r = k / 3, c = k - (k / 3) * 3;
                    Jccx[r * 72 + jj * 3 + c] = s;
                    if (r == 0) CCX[col * 3 + c] = s;
                } else {
                    CCX[(size_t)218 * RL + col * 3 + 0] = s;
                    CCX[(size_t)218 * RL + col * 3 + 1] = s;
                    CCX[(size_t)218 * RL + col * 3 + 2] = s;
                }
            }
        }
    }
}

// ---------------------------------------------------------------------------
// gemmchain: bid<168 GEMM | bid 168..175 vred | bid 176..687 chain.
// (Verified round 21.)
// ---------------------------------------------------------------------------
__global__ __launch_bounds__(256) void gemmchain(
    const unsigned short* __restrict__ Apack,
    const unsigned short* __restrict__ Bpack,
    float* __restrict__ partials,
    const float* __restrict__ vpart, float* __restrict__ CCX,
    const float* __restrict__ beta, const float* __restrict__ theta,
    const float* __restrict__ Jccx,
    unsigned short* __restrict__ Xbpack,
    float* __restrict__ Rg_ws, float* __restrict__ tA_ws)
{
    __shared__ __align__(16) char smem[2 * 7680 + 2 * 20480];   // 56320
    const int bid = blockIdx.x;
    const int t = threadIdx.x;

    if (bid >= NGEMM) {
        if (bid < NGEMM + 8) {
            const int tid = (bid - NGEMM) * 256 + t;
            if (tid < 456 * 4) {
                float s = 0.f;
                #pragma unroll 9
                for (int ch = 0; ch < NVCH; ++ch)
                    s += vpart[(size_t)ch * VPROW + tid];
                const int col = tid >> 2, q = tid & 3;
                if (q < 3) {
                    CCX[col * 3 + q] = s;
                } else {
                    CCX[(size_t)218 * RL + col * 3 + 0] = s;
                    CCX[(size_t)218 * RL + col * 3 + 1] = s;
                    CCX[(size_t)218 * RL + col * 3 + 2] = s;
                }
            }
            return;
        }
        float* F = (float*)smem;
        float* xs = F;                       // 218
        float (*Rl)[9] = (float(*)[9])(F + 224);
        float (*Rg)[9] = (float(*)[9])(F + 440);
        float (*tg)[3] = (float(*)[3])(F + 656);
        float (*tA)[3] = (float(*)[3])(F + 728);
        float (*Jl)[3] = (float(*)[3])(F + 800);
        const int b = bid - (NGEMM + 8);

        if (t < 24) {
            const int i = t;
            const float tx = theta[b * 72 + 3 * i + 0];
            const float ty = theta[b * 72 + 3 * i + 1];
            const float tz = theta[b * 72 + 3 * i + 2];
            const float ax = tx + 1e-8f, ay = ty + 1e-8f, az = tz + 1e-8f;
            const float angle = sqrtf(ax * ax + ay * ay + az * az);
            const float half = 0.5f * angle;
            const float sh = sinf(half), chh = cosf(half);
            const float inv = 1.f / angle;
            float qw = chh, qx = sh * tx * inv, qy = sh * ty * inv, qz = sh * tz * inv;
            const float rn = 1.f / sqrtf(qw * qw + qx * qx + qy * qy + qz * qz);
            qw *= rn; qx *= rn; qy *= rn; qz *= rn;
            float R[9];
            R[0] = 1.f - 2.f * (qy * qy + qz * qz);
            R[1] = 2.f * (qx * qy - qw * qz);
            R[2] = 2.f * (qx * qz + qw * qy);
            R[3] = 2.f * (qx * qy + qw * qz);
            R[4] = 1.f - 2.f * (qx * qx + qz * qz);
            R[5] = 2.f * (qy * qz - qw * qx);
            R[6] = 2.f * (qx * qz - qw * qy);
            R[7] = 2.f * (qy * qz + qw * qx);
            R[8] = 1.f - 2.f * (qx * qx + qy * qy);
            #pragma unroll
            for (int e = 0; e < 9; ++e) Rl[i][e] = R[e];
            if (i >= 1) {
                #pragma unroll
                for (int e = 0; e < 9; ++e)
                    xs[11 + (i - 1) * 9 + e] = R[e] - ((e == 0 || e == 4 || e == 8) ? 1.f : 0.f);
            }
        } else if (t == 24) {
            xs[0] = 1.f;
        } else if (t >= 25 && t < 35) {
            xs[t - 24] = beta[b * NB + (t - 25)];
        }
        __syncthreads();

        if (t < 72) {
            const int jj = t / 3, c = t - (t / 3) * 3;
            float a = 0.f;
            #pragma unroll
            for (int r = 0; r <= 10; ++r)
                a += xs[r] * Jccx[r * 72 + jj * 3 + c];
            Jl[jj][c] = a;
        }
        __syncthreads();

        for (int lv = 0; lv < 9; ++lv) {
            const int beg = c_LOFF[lv];
            const int cnt = c_LOFF[lv + 1] - beg;
            if (t < cnt * 12) {
                const int li = t / 12, e = t - li * 12;
                const int j = beg + li;
                const int r = e >> 2, cc = e & 3;
                if (lv == 0) {
                    if (cc < 3) Rg[0][r * 3 + cc] = Rl[0][r * 3 + cc] * ((cc == 0) ? 1.f : -1.f);
                    else        tg[0][r] = Jl[0][r];
                } else {
                    const int p = c_PAR[j];
                    if (cc < 3) {
                        Rg[j][r * 3 + cc] = Rg[p][r * 3 + 0] * Rl[j][0 + cc]
                                          + Rg[p][r * 3 + 1] * Rl[j][3 + cc]
                                          + Rg[p][r * 3 + 2] * Rl[j][6 + cc];
                    } else {
                        const float t0 = Jl[j][0] - Jl[p][0];
                        const float t1 = Jl[j][1] - Jl[p][1];
                        const float t2 = Jl[j][2] - Jl[p][2];
                        tg[j][r] = Rg[p][r * 3 + 0] * t0 + Rg[p][r * 3 + 1] * t1
                                 + Rg[p][r * 3 + 2] * t2 + tg[p][r];
                    }
                }
            }
            __syncthreads();
        }

        if (t < 72) {
            const int i = t / 3, c = t - (t / 3) * 3;
            tA[i][c] = tg[i][c] - (Rg[i][c * 3 + 0] * Jl[i][0]
                                 + Rg[i][c * 3 + 1] * Jl[i][1]
                                 + Rg[i][c * 3 + 2] * Jl[i][2]);
        }
        __syncthreads();

        if (t < 224) {                   // k = t: 0..216 real, 217..223 ZERO pad
            const unsigned short hv = (t < 217) ? f2bf(xs[t + 1]) : (unsigned short)0;
            const int bt = b >> 5, brow = b & 31, kc = t >> 5, kk = t & 31;
            Xbpack[((size_t)(bt * 7 + kc) * 32 + brow) * 40 + kk] = hv;
        }
        if (t < 216) Rg_ws[(size_t)b * 216 + t] = ((const float*)Rg)[t];
        if (t < 72)  tA_ws[(size_t)b * 72 + t]  = ((const float*)tA)[t];
        return;
    }

    // ------------------------------ GEMM ----------------------------------
    const int ks = bid % KS2;
    const int nt = (bid / KS2) & 1;
    const int mt2 = bid / (KS2 * NT);
    const int w4 = t >> 6;
    const int lane15 = t & 15;
    const int kg = (t >> 4) & 3;
    const int kc0 = ks * KCP2;

    f32x4 acc[6][4];
    #pragma unroll
    for (int mf = 0; mf < 6; ++mf)
        #pragma unroll
        for (int nf = 0; nf < 4; ++nf) acc[mf][nf] = (f32x4){0.f, 0.f, 0.f, 0.f};

#define STAGE2(kc, buf) do { \
        _Pragma("unroll") \
        for (int q = 0; q < 3; ++q) { \
            if (t < 160) \
                GLOAD_LDS16((const char*)Apack + ((size_t)((3 * mt2 + q) * KC + (kc))) * 2560 + t * 16, \
                            smem + (buf) * 7680 + q * 2560 + (t >> 6) * 1024); \
        } \
        _Pragma("unroll") \
        for (int it = 0; it < 5; ++it) \
            GLOAD_LDS16((const char*)Bpack + ((size_t)(nt * KC + (kc))) * 20480 + (it * 256 + t) * 16, \
                        smem + 15360 + (buf) * 20480 + it * 4096 + (t >> 6) * 1024); \
    } while (0)

    STAGE2(kc0, 0);
    asm volatile("s_waitcnt vmcnt(0)" ::: "memory");
    __syncthreads();

    for (int i = 0; i < KCP2; ++i) {
        const int cur = i & 1;
        if (i < KCP2 - 1) STAGE2(kc0 + i + 1, cur ^ 1);

        short8 af[6];
        #pragma unroll
        for (int mf = 0; mf < 6; ++mf)
            af[mf] = *reinterpret_cast<const short8*>(
                smem + cur * 7680 + (mf * 16 + lane15) * 80 + kg * 16);
        #pragma unroll
        for (int nf = 0; nf < 4; ++nf) {
            const short8 bf = *reinterpret_cast<const short8*>(
                smem + 15360 + cur * 20480 + (w4 * 64 + nf * 16 + lane15) * 80 + kg * 16);
            #pragma unroll
            for (int mf = 0; mf < 6; ++mf)
                acc[mf][nf] = __builtin_amdgcn_mfma_f32_16x16x32_bf16(af[mf], bf, acc[mf][nf], 0, 0, 0);
        }
        if (i < KCP2 - 1) {
            asm volatile("s_waitcnt vmcnt(0)" ::: "memory");
            __syncthreads();
        }
    }
#undef STAGE2

    #pragma unroll
    for (int mf = 0; mf < 6; ++mf)
        #pragma unroll
        for (int nf = 0; nf < 4; ++nf) {
            const int m = mt2 * 96 + mf * 16 + kg * 4;
            const int col = nt * 256 + w4 * 64 + nf * 16 + lane15;
            #pragma unroll
            for (int reg = 0; reg < 4; ++reg)
                partials[((size_t)ks * MDIM + m + reg) * 512 + col] = acc[mf][nf][reg];
        }
}

// ---------------------------------------------------------------------------
// reduce: 336 blocks; sum 12 K-splits -> Cbpack bf16 ONLY (ROUND-22: the fp32
// CCX row 1..217 writes were dead — mgemm consumes Cbpack, joints reads row
// 218, Ml-base reads row 0).
// ---------------------------------------------------------------------------
__global__ __launch_bounds__(256) void reduce_k(
    const float* __restrict__ partials,
    unsigned short* __restrict__ Cbpack)
{
    const int idx = blockIdx.x * 256 + threadIdx.x;
    const int m = idx >> 7;
    const int col = (idx & 127) * 4;
    float4 s = {0.f, 0.f, 0.f, 0.f};
    #pragma unroll 6
    for (int ks = 0; ks < KS2; ++ks) {
        const float4 p = *reinterpret_cast<const float4*>(
            &partials[((size_t)ks * MDIM + m) * 512 + col]);
        s.x += p.x; s.y += p.y; s.z += p.z; s.w += p.w;
    }
    if (m < 657 && col < NCOLS) {
        const int r = m / 3, c = m - (m / 3) * 3;
        if (r != 0 && r != 218) {
            float sv[4] = {s.x, s.y, s.z, s.w};
            const int k = r - 1;                  // 0..216
            const int kc2 = k >> 5, kk = k & 31;
            #pragma unroll
            for (int u = 0; u < 4; ++u) {
                const int colIdx = (col + u) * 3 + c;
                if (colIdx < MLCOLS) {
                    const int ct2 = colIdx >> 8, colrow = colIdx & 255;
                    Cbpack[((size_t)(ct2 * 7 + kc2) * 256 + colrow) * 40 + kk] = f2bf(sv[u]);
                }
            }
        }
    }
}

// ---------------------------------------------------------------------------
// mgemm_mfma (ROUND-22): 32b x 128col tiles -> 16 bt x 11 ct' = 176 blocks
// (was 96 = 0.375 blk/CU, occupancy-limited). ct' maps into the 256-col
// Cbpack images: ct2 = ct'>>1, row offset (ct'&1)*128. LDS 25.6KB.
// ct'=10 touches poisoned colIdx 1368..1407 (finite tiny bf16); write guarded.
// ---------------------------------------------------------------------------
__global__ __launch_bounds__(256) void mgemm_mfma(
    const unsigned short* __restrict__ Xbpack,
    const unsigned short* __restrict__ Cbpack,
    const float* __restrict__ CCX,
    float* __restrict__ Ml)
{
    __shared__ __align__(16) char smem[2 * 2560 + 2 * 10240];   // 25600
    const int AOFF[2] = {0, 2560};
    const int BOFF[2] = {5120, 5120 + 10240};
    const int bid = blockIdx.x;
    const int ctp = bid % 11;          // 0..10 (128-col tiles)
    const int bt = bid / 11;           // 0..15
    const int t = threadIdx.x;
    const int w = t >> 6;
    const int lane15 = t & 15;
    const int kg = (t >> 4) & 3;
    const int mrow0 = (w & 1) * 16;
    const int ncol0 = (w >> 1) * 64;   // 2 col halves of 64

    const int ct2 = ctp >> 1;
    const size_t bsub = (size_t)(ctp & 1) * 128 * 80;   // byte offset of 128-row half

#define MSTG(kc, buf) do { \
        const char* ga = (const char*)Xbpack + ((size_t)(bt * 7 + (kc))) * 2560; \
        const char* gb = (const char*)Cbpack + ((size_t)(ct2 * 7 + (kc))) * 20480 + bsub; \
        if (t < 160) GLOAD_LDS16(ga + t * 16, smem + AOFF[buf] + (t >> 6) * 1024); \
        _Pragma("unroll") \
        for (int it = 0; it < 3; ++it) { \
            const int i_ = t + it * 256; \
            if (i_ < 640) \
                GLOAD_LDS16(gb + i_ * 16, smem + BOFF[buf] + (i_ >> 6) * 1024); \
        } \
    } while (0)

    f32x4 acc[4];
    #pragma unroll
    for (int f = 0; f < 4; ++f) acc[f] = (f32x4){0.f, 0.f, 0.f, 0.f};

    MSTG(0, 0);
    asm volatile("s_waitcnt vmcnt(0)" ::: "memory");
    __syncthreads();

    for (int i = 0; i < 7; ++i) {
        const int cur = i & 1;
        if (i < 6) MSTG(i + 1, cur ^ 1);

        const short8 af = *reinterpret_cast<const short8*>(
            smem + AOFF[cur] + (mrow0 + lane15) * 80 + kg * 16);
        #pragma unroll
        for (int f = 0; f < 4; ++f) {
            const short8 bf = *reinterpret_cast<const short8*>(
                smem + BOFF[cur] + (ncol0 + f * 16 + lane15) * 80 + kg * 16);
            acc[f] = __builtin_amdgcn_mfma_f32_16x16x32_bf16(af, bf, acc[f], 0, 0, 0);
        }
        if (i < 6) {
            asm volatile("s_waitcnt vmcnt(0)" ::: "memory");
            __syncthreads();
        }
    }
#undef MSTG

    #pragma unroll
    for (int f = 0; f < 4; ++f) {
        const int colp = ctp * 128 + ncol0 + f * 16 + lane15;
        if (colp < MLCOLS) {
            const float base = CCX[colp];          // row 0 (fp32 exact, xs[0]=1)
            const int bb = bt * 32 + mrow0 + kg * 4;
            #pragma unroll
            for (int reg = 0; reg < 4; ++reg)
                Ml[(size_t)(bb + reg) * MLCOLS + colp] = acc[f][reg] + base;
        }
    }
}

// ---------------------------------------------------------------------------
// joints: one block per b, 256 threads. (Verified.)
// ---------------------------------------------------------------------------
__global__ __launch_bounds__(256) void joints_k(
    const float* __restrict__ Ml, const float* __restrict__ Rg_ws,
    const float* __restrict__ tA_ws, const float* __restrict__ CCX,
    float* __restrict__ out)
{
    __shared__ float Mls[1368];
    __shared__ float Wj[1368];
    __shared__ float Rgs[216];
    __shared__ float tAs[72];
    const int b = blockIdx.x;
    const int t = threadIdx.x;

    for (int i = t; i < 342; i += 256) {
        reinterpret_cast<float4*>(Mls)[i] =
            reinterpret_cast<const float4*>(Ml + (size_t)b * 1368)[i];
        reinterpret_cast<float4*>(Wj)[i] =
            reinterpret_cast<const float4*>(CCX + (size_t)218 * RL)[i];
    }
    if (t < 216) Rgs[t] = Rg_ws[(size_t)b * 216 + t];
    if (t < 72)  tAs[t] = tA_ws[(size_t)b * 72 + t];
    __syncthreads();

    if (t < 57) {
        const int j = t / 3, c = t - (t / 3) * 3;
        float a = 0.f;
        #pragma unroll
        for (int i = 0; i < 24; ++i) {
            const int mb = (j * 24 + i) * 3;
            a += Rgs[i * 9 + c * 3 + 0] * Mls[mb + 0]
               + Rgs[i * 9 + c * 3 + 1] * Mls[mb + 1]
               + Rgs[i * 9 + c * 3 + 2] * Mls[mb + 2]
               + tAs[i * 3 + c] * Wj[mb];
        }
        out[b * 57 + t] = a;
    }
}

extern "C" void kernel_launch(void* const* d_in, const int* in_sizes, int n_in,
                              void* d_out, int out_size, void* d_ws, size_t ws_size,
                              hipStream_t stream) {
    const float* beta  = (const float*)d_in[0];
    const float* theta = (const float*)d_in[1];
    const float* vt    = (const float*)d_in[2];
    const float* sd    = (const float*)d_in[3];
    const float* pd    = (const float*)d_in[4];
    const float* Jreg  = (const float*)d_in[5];
    const float* jr    = (const float*)d_in[6];
    const float* w     = (const float*)d_in[7];
    float* outp = (float*)d_out;

    // ws layout (floats): CCX | partials(12) | Apack | Bpack | Jccx | Rg | tA |
    //                     vpart | Ml | Xbpack | Cbpack
    float* CCX = (float*)d_ws;
    float* partials = CCX + CCX_ELEMS;
    unsigned short* Apack = (unsigned short*)(partials + (size_t)KS2 * MDIM * 512);
    unsigned short* Bpack = Apack + (size_t)MT * KC * AIMG;
    float* Jccx  = (float*)(Bpack + (size_t)NT * KC * BIMG);
    float* Rg_ws = Jccx + 792;
    float* tA_ws = Rg_ws + 512 * 216;
    float* vpart = tA_ws + 512 * 72;
    float* Ml    = vpart + (size_t)NVCH * VPROW;
    unsigned short* Xbpack = (unsigned short*)(Ml + (size_t)512 * MLCOLS);
    unsigned short* Cbpack = Xbpack + (size_t)16 * 7 * 32 * 40;

    prep<<<491, 256, 0, stream>>>(vt, sd, pd, Jreg, jr, w, Apack, Bpack, CCX, Jccx, vpart);
    gemmchain<<<NGEMM + 8 + 512, 256, 0, stream>>>(Apack, Bpack, partials, vpart, CCX,
                                                   beta, theta, Jccx,
                                                   Xbpack, Rg_ws, tA_ws);
    reduce_k<<<336, 256, 0, stream>>>(partials, Cbpack);
    mgemm_mfma<<<176, 256, 0, stream>>>(Xbpack, Cbpack, CCX, Ml);
    joints_k<<<512, 256, 0, stream>>>(Ml, Rg_ws, tA_ws, CCX, outp);
}

// Round 23
// 66.620 us; speedup vs baseline: 1.2899x; 1.0086x over previous
//
#include <hip/hip_runtime.h>

#define VNUM 6890
#define SLEN 20670      // V*3
#define NJ 24
#define NJR 19
#define NB 10
#define NROWS 219
#define NCOLS 480
#define RL 1440         // NCOLS*3
#define CCX_ELEMS (NROWS * RL)
#define MLCOLS 1368

#define MDIM 672
#define MT   21         // 32-row A granules
#define NT   2
#define KC   216        // k-chunks of 32
#define AROW 40         // 32 data + 8 pad, bf16
#define AIMG (32 * AROW)
#define BIMG (256 * AROW)

// gemm96: 96-row tiles, 12 K-splits of 18 chunks
#define MT2 7
#define KS2 12
#define KCP2 18
#define NGEMM (MT2 * NT * KS2)   // 168

#define NVCH 27         // v-chunks of 256 for fp32 rows 0/218
#define VPROW 1824      // 456 cols * 4 vals per chunk

typedef short short8 __attribute__((ext_vector_type(8)));
typedef unsigned short u16x4 __attribute__((ext_vector_type(4)));
typedef float f32x4 __attribute__((ext_vector_type(4)));

#define GLOAD_LDS16(g, l) \
    __builtin_amdgcn_global_load_lds((const __attribute__((address_space(1))) void*)(g), \
                                     (__attribute__((address_space(3))) void*)(l), 16, 0, 0)

__constant__ int c_PAR[24]  = {0,0,0,0,1,2,3,4,5,6,7,8,9,9,9,12,13,14,16,17,18,19,20,21};
__constant__ int c_LOFF[10] = {0,1,4,7,10,15,18,20,22,24};

__device__ __forceinline__ unsigned short f2bf(float f) {
    union { float f; unsigned int u; } x; x.f = f;
    unsigned int r = x.u + 0x7fffu + ((x.u >> 16) & 1u);   // RNE
    return (unsigned short)(r >> 16);
}

// ---------------------------------------------------------------------------
// prep: packA(0..223) | packB(224..439) | vchunk(440..466) | Jcols(467..490).
// (Verified rounds 13-22, byte-identical.)
// ---------------------------------------------------------------------------
__global__ __launch_bounds__(256) void prep(
    const float* __restrict__ vt, const float* __restrict__ sd,
    const float* __restrict__ pd, const float* __restrict__ Jreg,
    const float* __restrict__ jr, const float* __restrict__ w,
    unsigned short* __restrict__ Apack, unsigned short* __restrict__ Bpack,
    float* __restrict__ CCX, float* __restrict__ Jccx,
    float* __restrict__ vpart)
{
    __shared__ float jrl_b[256 * NJR];   // 19456 B
    __shared__ float wl_b[256 * NJ];     // 24576 B
    __shared__ float vtl[256 * 3];       //  3072 B

    const int bid = blockIdx.x;
    const int t = threadIdx.x;

    if (bid < 224) {
        const int r = bid;
        const float* src = (r == 0) ? vt
                         : (r <= 10 ? sd + (size_t)(r - 1) * SLEN
                         : (r <= 217 ? pd + (size_t)(r - 11) * SLEN : nullptr));
        for (int g = t; g < 1728; g += 256) {
            const int v = 4 * g;
            float lv[12];
            if (r <= 217) {
                if (3 * v + 12 <= SLEN) {
                    const float4 a = *reinterpret_cast<const float4*>(src + 3 * v);
                    const float4 b4 = *reinterpret_cast<const float4*>(src + 3 * v + 4);
                    const float4 c4 = *reinterpret_cast<const float4*>(src + 3 * v + 8);
                    lv[0]=a.x; lv[1]=a.y; lv[2]=a.z; lv[3]=a.w;
                    lv[4]=b4.x; lv[5]=b4.y; lv[6]=b4.z; lv[7]=b4.w;
                    lv[8]=c4.x; lv[9]=c4.y; lv[10]=c4.z; lv[11]=c4.w;
                } else {
                    #pragma unroll
                    for (int l = 0; l < 12; ++l) {
                        const int idx = 3 * v + l;
                        lv[l] = (idx < SLEN) ? src[idx] : 0.f;
                    }
                }
            } else if (r == 218) {
                #pragma unroll
                for (int l = 0; l < 12; ++l) lv[l] = (v + l / 3 < VNUM) ? 1.f : 0.f;
            } else {
                #pragma unroll
                for (int l = 0; l < 12; ++l) lv[l] = 0.f;
            }
            const int kc = v >> 5, kk = v & 31;
            #pragma unroll
            for (int c = 0; c < 3; ++c) {
                const int m = 3 * r + c;
                const int mt = m >> 5, mrow = m & 31;
                u16x4 s = {f2bf(lv[c]), f2bf(lv[3 + c]), f2bf(lv[6 + c]), f2bf(lv[9 + c])};
                *reinterpret_cast<u16x4*>(
                    &Apack[((size_t)(mt * KC + kc) * 32 + mrow) * AROW + kk]) = s;
            }
        }
    } else if (bid < 440) {
        const int kc = bid - 224;
        const int v0 = kc * 32;
        float* jrl = jrl_b;
        float* wl  = jrl_b + 32 * NJR;
        float* Jl2 = wl + 32 * NJ;
        for (int i = t; i < 32 * NJR; i += 256) {
            const int g = v0 * NJR + i;
            jrl[i] = (g < VNUM * NJR) ? jr[g] : 0.f;
        }
        for (int i = t; i < 32 * NJ; i += 256) {
            const int g = v0 * NJ + i;
            wl[i]  = (g < VNUM * NJ) ? w[g] : 0.f;
            Jl2[i] = (g < VNUM * NJ) ? Jreg[g] : 0.f;
        }
        __syncthreads();
        #pragma unroll
        for (int nt = 0; nt < NT; ++nt) {
            const int col = nt * 256 + t;
            const int j = col / 24, i = col - j * 24;
            short8 ov[4];
            #pragma unroll
            for (int kk = 0; kk < 32; ++kk) {
                float val = 0.f;
                if (v0 + kk < VNUM) {
                    if (col < 456)      val = jrl[kk * NJR + j] * wl[kk * NJ + i];
                    else if (col < 480) val = Jl2[kk * NJ + (col - 456)];
                }
                ov[kk >> 3][kk & 7] = (short)f2bf(val);
            }
            unsigned short* dst = Bpack + ((size_t)(nt * KC + kc) * 256 + t) * AROW;
            #pragma unroll
            for (int q = 0; q < 4; ++q)
                *reinterpret_cast<short8*>(dst + 8 * q) = ov[q];
        }
    } else if (bid < 467) {
        const int ch = bid - 440;
        const int v0 = ch * 256;
        for (int i = t; i < 256 * NJR; i += 256) {
            const int g = v0 * NJR + i;
            jrl_b[i] = (g < VNUM * NJR) ? jr[g] : 0.f;
        }
        for (int i = t; i < 256 * NJ; i += 256) {
            const int g = v0 * NJ + i;
            wl_b[i] = (g < VNUM * NJ) ? w[g] : 0.f;
        }
        for (int i = t; i < 256 * 3; i += 256) {
            const int g = v0 * 3 + i;
            vtl[i] = (g < VNUM * 3) ? vt[g] : 0.f;
        }
        __syncthreads();
        if (t < 228) {
            #pragma unroll
            for (int cc2 = 0; cc2 < 2; ++cc2) {
                const int col = t + cc2 * 228;
                const int j = col / 24, i2 = col - j * 24;
                float s0 = 0.f, s1 = 0.f, s2 = 0.f, s3 = 0.f;
                #pragma unroll 4
                for (int v = 0; v < 256; ++v) {
                    const float coef = jrl_b[v * NJR + j] * wl_b[v * NJ + i2];
                    s0 += coef * vtl[v * 3 + 0];
                    s1 += coef * vtl[v * 3 + 1];
                    s2 += coef * vtl[v * 3 + 2];
                    s3 += coef;
                }
                float4 pv = {s0, s1, s2, s3};
                *reinterpret_cast<float4*>(&vpart[(size_t)ch * VPROW + col * 4]) = pv;
            }
        }
    } else {
        const int jj = bid - 467;        // 0..23
        const int col = 456 + jj;
        float ja[34];
        #pragma unroll
        for (int k = 0; k < 34; ++k) ja[k] = 0.f;
        for (int v = t; v < VNUM; v += 256) {
            const float coef = Jreg[v * NJ + jj];
            ja[33] += coef;
            #pragma unroll
            for (int c = 0; c < 3; ++c) ja[c] += coef * vt[3 * v + c];
            #pragma unroll
            for (int r = 1; r <= 10; ++r)
                #pragma unroll
                for (int c = 0; c < 3; ++c)
                    ja[r * 3 + c] += coef * sd[(size_t)(r - 1) * SLEN + 3 * v + c];
        }
        float* red = jrl_b;              // [4][34]
        #pragma unroll
        for (int k = 0; k < 34; ++k) {
            float vv = ja[k];
            #pragma unroll
            for (int off = 32; off; off >>= 1) vv += __shfl_down(vv, off);
            if ((t & 63) == 0) red[(t >> 6) * 34 + k] = vv;
        }
        __syncthreads();
        if (t == 0) {
            #pragma unroll
            for (int k = 0; k < 34; ++k) {
                const float s = red[0 * 34 + k] + red[1 * 34 + k]
                              + red[2 * 34 + k] + red[3 * 34 + k];
                if (k < 33) {
                    const int r = k / 3, c = k - (k / 3) * 3;
                    Jccx[r * 72 + jj * 3 + c] = s;
                    if (r == 0) CCX[col * 3 + c] = s;
                } else {
                    CCX[(size_t)218 * RL + col * 3 + 0] = s;
                    CCX[(size_t)218 * RL + col * 3 + 1] = s;
                    CCX[(size_t)218 * RL + col * 3 + 2] = s;
                }
            }
        }
    }
}

// ---------------------------------------------------------------------------
// gemmchain: bid<168 GEMM | bid 168..175 vred | bid 176..687 chain.
// (Verified rounds 21-22, byte-identical.)
// ---------------------------------------------------------------------------
__global__ __launch_bounds__(256) void gemmchain(
    const unsigned short* __restrict__ Apack,
    const unsigned short* __restrict__ Bpack,
    float* __restrict__ partials,
    const float* __restrict__ vpart, float* __restrict__ CCX,
    const float* __restrict__ beta, const float* __restrict__ theta,
    const float* __restrict__ Jccx,
    unsigned short* __restrict__ Xbpack,
    float* __restrict__ Rg_ws, float* __restrict__ tA_ws)
{
    __shared__ __align__(16) char smem[2 * 7680 + 2 * 20480];   // 56320
    const int bid = blockIdx.x;
    const int t = threadIdx.x;

    if (bid >= NGEMM) {
        if (bid < NGEMM + 8) {
            const int tid = (bid - NGEMM) * 256 + t;
            if (tid < 456 * 4) {
                float s = 0.f;
                #pragma unroll 9
                for (int ch = 0; ch < NVCH; ++ch)
                    s += vpart[(size_t)ch * VPROW + tid];
                const int col = tid >> 2, q = tid & 3;
                if (q < 3) {
                    CCX[col * 3 + q] = s;
                } else {
                    CCX[(size_t)218 * RL + col * 3 + 0] = s;
                    CCX[(size_t)218 * RL + col * 3 + 1] = s;
                    CCX[(size_t)218 * RL + col * 3 + 2] = s;
                }
            }
            return;
        }
        float* F = (float*)smem;
        float* xs = F;                       // 218
        float (*Rl)[9] = (float(*)[9])(F + 224);
        float (*Rg)[9] = (float(*)[9])(F + 440);
        float (*tg)[3] = (float(*)[3])(F + 656);
        float (*tA)[3] = (float(*)[3])(F + 728);
        float (*Jl)[3] = (float(*)[3])(F + 800);
        const int b = bid - (NGEMM + 8);

        if (t < 24) {
            const int i = t;
            const float tx = theta[b * 72 + 3 * i + 0];
            const float ty = theta[b * 72 + 3 * i + 1];
            const float tz = theta[b * 72 + 3 * i + 2];
            const float ax = tx + 1e-8f, ay = ty + 1e-8f, az = tz + 1e-8f;
            const float angle = sqrtf(ax * ax + ay * ay + az * az);
            const float half = 0.5f * angle;
            const float sh = sinf(half), chh = cosf(half);
            const float inv = 1.f / angle;
            float qw = chh, qx = sh * tx * inv, qy = sh * ty * inv, qz = sh * tz * inv;
            const float rn = 1.f / sqrtf(qw * qw + qx * qx + qy * qy + qz * qz);
            qw *= rn; qx *= rn; qy *= rn; qz *= rn;
            float R[9];
            R[0] = 1.f - 2.f * (qy * qy + qz * qz);
            R[1] = 2.f * (qx * qy - qw * qz);
            R[2] = 2.f * (qx * qz + qw * qy);
            R[3] = 2.f * (qx * qy + qw * qz);
            R[4] = 1.f - 2.f * (qx * qx + qz * qz);
            R[5] = 2.f * (qy * qz - qw * qx);
            R[6] = 2.f * (qx * qz - qw * qy);
            R[7] = 2.f * (qy * qz + qw * qx);
            R[8] = 1.f - 2.f * (qx * qx + qy * qy);
            #pragma unroll
            for (int e = 0; e < 9; ++e) Rl[i][e] = R[e];
            if (i >= 1) {
                #pragma unroll
                for (int e = 0; e < 9; ++e)
                    xs[11 + (i - 1) * 9 + e] = R[e] - ((e == 0 || e == 4 || e == 8) ? 1.f : 0.f);
            }
        } else if (t == 24) {
            xs[0] = 1.f;
        } else if (t >= 25 && t < 35) {
            xs[t - 24] = beta[b * NB + (t - 25)];
        }
        __syncthreads();

        if (t < 72) {
            const int jj = t / 3, c = t - (t / 3) * 3;
            float a = 0.f;
            #pragma unroll
            for (int r = 0; r <= 10; ++r)
                a += xs[r] * Jccx[r * 72 + jj * 3 + c];
            Jl[jj][c] = a;
        }
        __syncthreads();

        for (int lv = 0; lv < 9; ++lv) {
            const int beg = c_LOFF[lv];
            const int cnt = c_LOFF[lv + 1] - beg;
            if (t < cnt * 12) {
                const int li = t / 12, e = t - li * 12;
                const int j = beg + li;
                const int r = e >> 2, cc = e & 3;
                if (lv == 0) {
                    if (cc < 3) Rg[0][r * 3 + cc] = Rl[0][r * 3 + cc] * ((cc == 0) ? 1.f : -1.f);
                    else        tg[0][r] = Jl[0][r];
                } else {
                    const int p = c_PAR[j];
                    if (cc < 3) {
                        Rg[j][r * 3 + cc] = Rg[p][r * 3 + 0] * Rl[j][0 + cc]
                                          + Rg[p][r * 3 + 1] * Rl[j][3 + cc]
                                          + Rg[p][r * 3 + 2] * Rl[j][6 + cc];
                    } else {
                        const float t0 = Jl[j][0] - Jl[p][0];
                        const float t1 = Jl[j][1] - Jl[p][1];
                        const float t2 = Jl[j][2] - Jl[p][2];
                        tg[j][r] = Rg[p][r * 3 + 0] * t0 + Rg[p][r * 3 + 1] * t1
                                 + Rg[p][r * 3 + 2] * t2 + tg[p][r];
                    }
                }
            }
            __syncthreads();
        }

        if (t < 72) {
            const int i = t / 3, c = t - (t / 3) * 3;
            tA[i][c] = tg[i][c] - (Rg[i][c * 3 + 0] * Jl[i][0]
                                 + Rg[i][c * 3 + 1] * Jl[i][1]
                                 + Rg[i][c * 3 + 2] * Jl[i][2]);
        }
        __syncthreads();

        if (t < 224) {                   // k = t: 0..216 real, 217..223 ZERO pad
            const unsigned short hv = (t < 217) ? f2bf(xs[t + 1]) : (unsigned short)0;
            const int bt = b >> 5, brow = b & 31, kc = t >> 5, kk = t & 31;
            Xbpack[((size_t)(bt * 7 + kc) * 32 + brow) * 40 + kk] = hv;
        }
        if (t < 216) Rg_ws[(size_t)b * 216 + t] = ((const float*)Rg)[t];
        if (t < 72)  tA_ws[(size_t)b * 72 + t]  = ((const float*)tA)[t];
        return;
    }

    // ------------------------------ GEMM ----------------------------------
    const int ks = bid % KS2;
    const int nt = (bid / KS2) & 1;
    const int mt2 = bid / (KS2 * NT);
    const int w4 = t >> 6;
    const int lane15 = t & 15;
    const int kg = (t >> 4) & 3;
    const int kc0 = ks * KCP2;

    f32x4 acc[6][4];
    #pragma unroll
    for (int mf = 0; mf < 6; ++mf)
        #pragma unroll
        for (int nf = 0; nf < 4; ++nf) acc[mf][nf] = (f32x4){0.f, 0.f, 0.f, 0.f};

#define STAGE2(kc, buf) do { \
        _Pragma("unroll") \
        for (int q = 0; q < 3; ++q) { \
            if (t < 160) \
                GLOAD_LDS16((const char*)Apack + ((size_t)((3 * mt2 + q) * KC + (kc))) * 2560 + t * 16, \
                            smem + (buf) * 7680 + q * 2560 + (t >> 6) * 1024); \
        } \
        _Pragma("unroll") \
        for (int it = 0; it < 5; ++it) \
            GLOAD_LDS16((const char*)Bpack + ((size_t)(nt * KC + (kc))) * 20480 + (it * 256 + t) * 16, \
                        smem + 15360 + (buf) * 20480 + it * 4096 + (t >> 6) * 1024); \
    } while (0)

    STAGE2(kc0, 0);
    asm volatile("s_waitcnt vmcnt(0)" ::: "memory");
    __syncthreads();

    for (int i = 0; i < KCP2; ++i) {
        const int cur = i & 1;
        if (i < KCP2 - 1) STAGE2(kc0 + i + 1, cur ^ 1);

        short8 af[6];
        #pragma unroll
        for (int mf = 0; mf < 6; ++mf)
            af[mf] = *reinterpret_cast<const short8*>(
                smem + cur * 7680 + (mf * 16 + lane15) * 80 + kg * 16);
        #pragma unroll
        for (int nf = 0; nf < 4; ++nf) {
            const short8 bf = *reinterpret_cast<const short8*>(
                smem + 15360 + cur * 20480 + (w4 * 64 + nf * 16 + lane15) * 80 + kg * 16);
            #pragma unroll
            for (int mf = 0; mf < 6; ++mf)
                acc[mf][nf] = __builtin_amdgcn_mfma_f32_16x16x32_bf16(af[mf], bf, acc[mf][nf], 0, 0, 0);
        }
        if (i < KCP2 - 1) {
            asm volatile("s_waitcnt vmcnt(0)" ::: "memory");
            __syncthreads();
        }
    }
#undef STAGE2

    #pragma unroll
    for (int mf = 0; mf < 6; ++mf)
        #pragma unroll
        for (int nf = 0; nf < 4; ++nf) {
            const int m = mt2 * 96 + mf * 16 + kg * 4;
            const int col = nt * 256 + w4 * 64 + nf * 16 + lane15;
            #pragma unroll
            for (int reg = 0; reg < 4; ++reg)
                partials[((size_t)ks * MDIM + m + reg) * 512 + col] = acc[mf][nf][reg];
        }
}

// ---------------------------------------------------------------------------
// reduce: 336 blocks; sum 12 K-splits -> Cbpack bf16 only. (Verified r22.)
// ---------------------------------------------------------------------------
__global__ __launch_bounds__(256) void reduce_k(
    const float* __restrict__ partials,
    unsigned short* __restrict__ Cbpack)
{
    const int idx = blockIdx.x * 256 + threadIdx.x;
    const int m = idx >> 7;
    const int col = (idx & 127) * 4;
    float4 s = {0.f, 0.f, 0.f, 0.f};
    #pragma unroll 6
    for (int ks = 0; ks < KS2; ++ks) {
        const float4 p = *reinterpret_cast<const float4*>(
            &partials[((size_t)ks * MDIM + m) * 512 + col]);
        s.x += p.x; s.y += p.y; s.z += p.z; s.w += p.w;
    }
    if (m < 657 && col < NCOLS) {
        const int r = m / 3, c = m - (m / 3) * 3;
        if (r != 0 && r != 218) {
            float sv[4] = {s.x, s.y, s.z, s.w};
            const int k = r - 1;                  // 0..216
            const int kc2 = k >> 5, kk = k & 31;
            #pragma unroll
            for (int u = 0; u < 4; ++u) {
                const int colIdx = (col + u) * 3 + c;
                if (colIdx < MLCOLS) {
                    const int ct2 = colIdx >> 8, colrow = colIdx & 255;
                    Cbpack[((size_t)(ct2 * 7 + kc2) * 256 + colrow) * 40 + kk] = f2bf(sv[u]);
                }
            }
        }
    }
}

// ---------------------------------------------------------------------------
// mgemm_mfma (ROUND-23): 32b x 64col tiles -> 16 bt x 22 ct' = 352 blocks
// (first mgemm grid above CU count; r21 96blk=11.6us, r22 176blk=8.7us).
// ct' maps into the 256-col Cbpack images: ct2 = ct'>>2, row offset
// (ct'&3)*64. LDS 15.4KB. ct'=21 touches poisoned colIdx 1368..1407
// (finite tiny bf16, A-pad zero); write guarded colp < 1368.
// ---------------------------------------------------------------------------
__global__ __launch_bounds__(256) void mgemm_mfma(
    const unsigned short* __restrict__ Xbpack,
    const unsigned short* __restrict__ Cbpack,
    const float* __restrict__ CCX,
    float* __restrict__ Ml)
{
    __shared__ __align__(16) char smem[2 * 2560 + 2 * 5120];   // 15360
    const int AOFF[2] = {0, 2560};
    const int BOFF[2] = {5120, 5120 + 5120};
    const int bid = blockIdx.x;
    const int ctp = bid % 22;          // 0..21 (64-col tiles)
    const int bt = bid / 22;           // 0..15
    const int t = threadIdx.x;
    const int w = t >> 6;
    const int lane15 = t & 15;
    const int kg = (t >> 4) & 3;
    const int mrow0 = (w & 1) * 16;
    const int ncol0 = (w >> 1) * 32;   // 2 col halves of 32

    const int ct2 = ctp >> 2;
    const size_t bsub = (size_t)(ctp & 3) * 64 * 80;   // byte offset of 64-row quarter

#define MSTG(kc, buf) do { \
        const char* ga = (const char*)Xbpack + ((size_t)(bt * 7 + (kc))) * 2560; \
        const char* gb = (const char*)Cbpack + ((size_t)(ct2 * 7 + (kc))) * 20480 + bsub; \
        if (t < 160) GLOAD_LDS16(ga + t * 16, smem + AOFF[buf] + (t >> 6) * 1024); \
        _Pragma("unroll") \
        for (int it = 0; it < 2; ++it) { \
            const int i_ = t + it * 256; \
            if (i_ < 320) \
                GLOAD_LDS16(gb + i_ * 16, smem + BOFF[buf] + (i_ >> 6) * 1024); \
        } \
    } while (0)

    f32x4 acc[2];
    #pragma unroll
    for (int f = 0; f < 2; ++f) acc[f] = (f32x4){0.f, 0.f, 0.f, 0.f};

    MSTG(0, 0);
    asm volatile("s_waitcnt vmcnt(0)" ::: "memory");
    __syncthreads();

    for (int i = 0; i < 7; ++i) {
        const int cur = i & 1;
        if (i < 6) MSTG(i + 1, cur ^ 1);

        const short8 af = *reinterpret_cast<const short8*>(
            smem + AOFF[cur] + (mrow0 + lane15) * 80 + kg * 16);
        #pragma unroll
        for (int f = 0; f < 2; ++f) {
            const short8 bf = *reinterpret_cast<const short8*>(
                smem + BOFF[cur] + (ncol0 + f * 16 + lane15) * 80 + kg * 16);
            acc[f] = __builtin_amdgcn_mfma_f32_16x16x32_bf16(af, bf, acc[f], 0, 0, 0);
        }
        if (i < 6) {
            asm volatile("s_waitcnt vmcnt(0)" ::: "memory");
            __syncthreads();
        }
    }
#undef MSTG

    #pragma unroll
    for (int f = 0; f < 2; ++f) {
        const int colp = ctp * 64 + ncol0 + f * 16 + lane15;
        if (colp < MLCOLS) {
            const float base = CCX[colp];          // row 0 (fp32 exact, xs[0]=1)
            const int bb = bt * 32 + mrow0 + kg * 4;
            #pragma unroll
            for (int reg = 0; reg < 4; ++reg)
                Ml[(size_t)(bb + reg) * MLCOLS + colp] = acc[f][reg] + base;
        }
    }
}

// ---------------------------------------------------------------------------
// joints: one block per b, 256 threads. (Verified.)
// ---------------------------------------------------------------------------
__global__ __launch_bounds__(256) void joints_k(
    const float* __restrict__ Ml, const float* __restrict__ Rg_ws,
    const float* __restrict__ tA_ws, const float* __restrict__ CCX,
    float* __restrict__ out)
{
    __shared__ float Mls[1368];
    __shared__ float Wj[1368];
    __shared__ float Rgs[216];
    __shared__ float tAs[72];
    const int b = blockIdx.x;
    const int t = threadIdx.x;

    for (int i = t; i < 342; i += 256) {
        reinterpret_cast<float4*>(Mls)[i] =
            reinterpret_cast<const float4*>(Ml + (size_t)b * 1368)[i];
        reinterpret_cast<float4*>(Wj)[i] =
            reinterpret_cast<const float4*>(CCX + (size_t)218 * RL)[i];
    }
    if (t < 216) Rgs[t] = Rg_ws[(size_t)b * 216 + t];
    if (t < 72)  tAs[t] = tA_ws[(size_t)b * 72 + t];
    __syncthreads();

    if (t < 57) {
        const int j = t / 3, c = t - (t / 3) * 3;
        float a = 0.f;
        #pragma unroll
        for (int i = 0; i < 24; ++i) {
            const int mb = (j * 24 + i) * 3;
            a += Rgs[i * 9 + c * 3 + 0] * Mls[mb + 0]
               + Rgs[i * 9 + c * 3 + 1] * Mls[mb + 1]
               + Rgs[i * 9 + c * 3 + 2] * Mls[mb + 2]
               + tAs[i * 3 + c] * Wj[mb];
        }
        out[b * 57 + t] = a;
    }
}

extern "C" void kernel_launch(void* const* d_in, const int* in_sizes, int n_in,
                              void* d_out, int out_size, void* d_ws, size_t ws_size,
                              hipStream_t stream) {
    const float* beta  = (const float*)d_in[0];
    const float* theta = (const float*)d_in[1];
    const float* vt    = (const float*)d_in[2];
    const float* sd    = (const float*)d_in[3];
    const float* pd    = (const float*)d_in[4];
    const float* Jreg  = (const float*)d_in[5];
    const float* jr    = (const float*)d_in[6];
    const float* w     = (const float*)d_in[7];
    float* outp = (float*)d_out;

    // ws layout (floats): CCX | partials(12) | Apack | Bpack | Jccx | Rg | tA |
    //                     vpart | Ml | Xbpack | Cbpack
    float* CCX = (float*)d_ws;
    float* partials = CCX + CCX_ELEMS;
    unsigned short* Apack = (unsigned short*)(partials + (size_t)KS2 * MDIM * 512);
    unsigned short* Bpack = Apack + (size_t)MT * KC * AIMG;
    float* Jccx  = (float*)(Bpack + (size_t)NT * KC * BIMG);
    float* Rg_ws = Jccx + 792;
    float* tA_ws = Rg_ws + 512 * 216;
    float* vpart = tA_ws + 512 * 72;
    float* Ml    = vpart + (size_t)NVCH * VPROW;
    unsigned short* Xbpack = (unsigned short*)(Ml + (size_t)512 * MLCOLS);
    unsigned short* Cbpack = Xbpack + (size_t)16 * 7 * 32 * 40;

    prep<<<491, 256, 0, stream>>>(vt, sd, pd, Jreg, jr, w, Apack, Bpack, CCX, Jccx, vpart);
    gemmchain<<<NGEMM + 8 + 512, 256, 0, stream>>>(Apack, Bpack, partials, vpart, CCX,
                                                   beta, theta, Jccx,
                                                   Xbpack, Rg_ws, tA_ws);
    reduce_k<<<336, 256, 0, stream>>>(partials, Cbpack);
    mgemm_mfma<<<352, 256, 0, stream>>>(Xbpack, Cbpack, CCX, Ml);
    joints_k<<<512, 256, 0, stream>>>(Ml, Rg_ws, tA_ws, CCX, outp);
}

// Round 24
// 64.654 us; speedup vs baseline: 1.3291x; 1.0304x over previous
//
#include <hip/hip_runtime.h>

#define VNUM 6890
#define SLEN 20670      // V*3
#define NJ 24
#define NJR 19
#define NB 10
#define NROWS 219
#define NCOLS 480
#define RL 1440         // NCOLS*3
#define CCX_ELEMS (NROWS * RL)
#define MLCOLS 1368

#define MDIM 672
#define MT   21         // 32-row A granules
#define NT   2
#define KC   216        // k-chunks of 32
#define AROW 40         // 32 data + 8 pad, bf16
#define AIMG (32 * AROW)
#define BIMG (256 * AROW)

// gemm96: 96-row tiles, 12 K-splits of 18 chunks
#define MT2 7
#define KS2 12
#define KCP2 18
#define NGEMM (MT2 * NT * KS2)   // 168

#define NVCH 27         // v-chunks of 256 for fp32 rows 0/218
#define VPROW 1824      // 456 cols * 4 vals per chunk

typedef short short8 __attribute__((ext_vector_type(8)));
typedef unsigned short u16x4 __attribute__((ext_vector_type(4)));
typedef float f32x4 __attribute__((ext_vector_type(4)));

#define GLOAD_LDS16(g, l) \
    __builtin_amdgcn_global_load_lds((const __attribute__((address_space(1))) void*)(g), \
                                     (__attribute__((address_space(3))) void*)(l), 16, 0, 0)

__constant__ int c_PAR[24]  = {0,0,0,0,1,2,3,4,5,6,7,8,9,9,9,12,13,14,16,17,18,19,20,21};
__constant__ int c_LOFF[10] = {0,1,4,7,10,15,18,20,22,24};

__device__ __forceinline__ unsigned short f2bf(float f) {
    union { float f; unsigned int u; } x; x.f = f;
    unsigned int r = x.u + 0x7fffu + ((x.u >> 16) & 1u);   // RNE
    return (unsigned short)(r >> 16);
}
__device__ __forceinline__ float bf2f(unsigned short h) {
    union { unsigned int u; float f; } x; x.u = ((unsigned int)h) << 16;
    return x.f;
}

// ---------------------------------------------------------------------------
// prep: packA(0..223) | packB(224..439) | vchunk(440..466) | Jcols(467..490).
// (Verified rounds 13-23, byte-identical.)
// ---------------------------------------------------------------------------
__global__ __launch_bounds__(256) void prep(
    const float* __restrict__ vt, const float* __restrict__ sd,
    const float* __restrict__ pd, const float* __restrict__ Jreg,
    const float* __restrict__ jr, const float* __restrict__ w,
    unsigned short* __restrict__ Apack, unsigned short* __restrict__ Bpack,
    float* __restrict__ CCX, float* __restrict__ Jccx,
    float* __restrict__ vpart)
{
    __shared__ float jrl_b[256 * NJR];   // 19456 B
    __shared__ float wl_b[256 * NJ];     // 24576 B
    __shared__ float vtl[256 * 3];       //  3072 B

    const int bid = blockIdx.x;
    const int t = threadIdx.x;

    if (bid < 224) {
        const int r = bid;
        const float* src = (r == 0) ? vt
                         : (r <= 10 ? sd + (size_t)(r - 1) * SLEN
                         : (r <= 217 ? pd + (size_t)(r - 11) * SLEN : nullptr));
        for (int g = t; g < 1728; g += 256) {
            const int v = 4 * g;
            float lv[12];
            if (r <= 217) {
                if (3 * v + 12 <= SLEN) {
                    const float4 a = *reinterpret_cast<const float4*>(src + 3 * v);
                    const float4 b4 = *reinterpret_cast<const float4*>(src + 3 * v + 4);
                    const float4 c4 = *reinterpret_cast<const float4*>(src + 3 * v + 8);
                    lv[0]=a.x; lv[1]=a.y; lv[2]=a.z; lv[3]=a.w;
                    lv[4]=b4.x; lv[5]=b4.y; lv[6]=b4.z; lv[7]=b4.w;
                    lv[8]=c4.x; lv[9]=c4.y; lv[10]=c4.z; lv[11]=c4.w;
                } else {
                    #pragma unroll
                    for (int l = 0; l < 12; ++l) {
                        const int idx = 3 * v + l;
                        lv[l] = (idx < SLEN) ? src[idx] : 0.f;
                    }
                }
            } else if (r == 218) {
                #pragma unroll
                for (int l = 0; l < 12; ++l) lv[l] = (v + l / 3 < VNUM) ? 1.f : 0.f;
            } else {
                #pragma unroll
                for (int l = 0; l < 12; ++l) lv[l] = 0.f;
            }
            const int kc = v >> 5, kk = v & 31;
            #pragma unroll
            for (int c = 0; c < 3; ++c) {
                const int m = 3 * r + c;
                const int mt = m >> 5, mrow = m & 31;
                u16x4 s = {f2bf(lv[c]), f2bf(lv[3 + c]), f2bf(lv[6 + c]), f2bf(lv[9 + c])};
                *reinterpret_cast<u16x4*>(
                    &Apack[((size_t)(mt * KC + kc) * 32 + mrow) * AROW + kk]) = s;
            }
        }
    } else if (bid < 440) {
        const int kc = bid - 224;
        const int v0 = kc * 32;
        float* jrl = jrl_b;
        float* wl  = jrl_b + 32 * NJR;
        float* Jl2 = wl + 32 * NJ;
        for (int i = t; i < 32 * NJR; i += 256) {
            const int g = v0 * NJR + i;
            jrl[i] = (g < VNUM * NJR) ? jr[g] : 0.f;
        }
        for (int i = t; i < 32 * NJ; i += 256) {
            const int g = v0 * NJ + i;
            wl[i]  = (g < VNUM * NJ) ? w[g] : 0.f;
            Jl2[i] = (g < VNUM * NJ) ? Jreg[g] : 0.f;
        }
        __syncthreads();
        #pragma unroll
        for (int nt = 0; nt < NT; ++nt) {
            const int col = nt * 256 + t;
            const int j = col / 24, i = col - j * 24;
            short8 ov[4];
            #pragma unroll
            for (int kk = 0; kk < 32; ++kk) {
                float val = 0.f;
                if (v0 + kk < VNUM) {
                    if (col < 456)      val = jrl[kk * NJR + j] * wl[kk * NJ + i];
                    else if (col < 480) val = Jl2[kk * NJ + (col - 456)];
                }
                ov[kk >> 3][kk & 7] = (short)f2bf(val);
            }
            unsigned short* dst = Bpack + ((size_t)(nt * KC + kc) * 256 + t) * AROW;
            #pragma unroll
            for (int q = 0; q < 4; ++q)
                *reinterpret_cast<short8*>(dst + 8 * q) = ov[q];
        }
    } else if (bid < 467) {
        const int ch = bid - 440;
        const int v0 = ch * 256;
        for (int i = t; i < 256 * NJR; i += 256) {
            const int g = v0 * NJR + i;
            jrl_b[i] = (g < VNUM * NJR) ? jr[g] : 0.f;
        }
        for (int i = t; i < 256 * NJ; i += 256) {
            const int g = v0 * NJ + i;
            wl_b[i] = (g < VNUM * NJ) ? w[g] : 0.f;
        }
        for (int i = t; i < 256 * 3; i += 256) {
            const int g = v0 * 3 + i;
            vtl[i] = (g < VNUM * 3) ? vt[g] : 0.f;
        }
        __syncthreads();
        if (t < 228) {
            #pragma unroll
            for (int cc2 = 0; cc2 < 2; ++cc2) {
                const int col = t + cc2 * 228;
                const int j = col / 24, i2 = col - j * 24;
                float s0 = 0.f, s1 = 0.f, s2 = 0.f, s3 = 0.f;
                #pragma unroll 4
                for (int v = 0; v < 256; ++v) {
                    const float coef = jrl_b[v * NJR + j] * wl_b[v * NJ + i2];
                    s0 += coef * vtl[v * 3 + 0];
                    s1 += coef * vtl[v * 3 + 1];
                    s2 += coef * vtl[v * 3 + 2];
                    s3 += coef;
                }
                float4 pv = {s0, s1, s2, s3};
                *reinterpret_cast<float4*>(&vpart[(size_t)ch * VPROW + col * 4]) = pv;
            }
        }
    } else {
        const int jj = bid - 467;        // 0..23
        const int col = 456 + jj;
        float ja[34];
        #pragma unroll
        for (int k = 0; k < 34; ++k) ja[k] = 0.f;
        for (int v = t; v < VNUM; v += 256) {
            const float coef = Jreg[v * NJ + jj];
            ja[33] += coef;
            #pragma unroll
            for (int c = 0; c < 3; ++c) ja[c] += coef * vt[3 * v + c];
            #pragma unroll
            for (int r = 1; r <= 10; ++r)
                #pragma unroll
                for (int c = 0; c < 3; ++c)
                    ja[r * 3 + c] += coef * sd[(size_t)(r - 1) * SLEN + 3 * v + c];
        }
        float* red = jrl_b;              // [4][34]
        #pragma unroll
        for (int k = 0; k < 34; ++k) {
            float vv = ja[k];
            #pragma unroll
            for (int off = 32; off; off >>= 1) vv += __shfl_down(vv, off);
            if ((t & 63) == 0) red[(t >> 6) * 34 + k] = vv;
        }
        __syncthreads();
        if (t == 0) {
            #pragma unroll
            for (int k = 0; k < 34; ++k) {
                const float s = red[0 * 34 + k] + red[1 * 34 + k]
                              + red[2 * 34 + k] + red[3 * 34 + k];
                if (k < 33) {
                    const int r = k / 3, c = k - (k / 3) * 3;
                    Jccx[r * 72 + jj * 3 + c] = s;
                    if (r == 0) CCX[col * 3 + c] = s;
                } else {
                    CCX[(size_t)218 * RL + col * 3 + 0] = s;
                    CCX[(size_t)218 * RL + col * 3 + 1] = s;
                    CCX[(size_t)218 * RL + col * 3 + 2] = s;
                }
            }
        }
    }
}

// ---------------------------------------------------------------------------
// gemmchain: bid<168 GEMM | bid 168..175 vred | bid 176..687 chain.
// ROUND-24 CHANGE (GEMM epilogue only): partials stored as bf16 (halves the
// 16.5MB round-trip; CCX rows 1..217 get bf16-rounded in Cbpack anyway, and
// 12-partial bf16 accumulation error is same order as the single rounding).
// ---------------------------------------------------------------------------
__global__ __launch_bounds__(256) void gemmchain(
    const unsigned short* __restrict__ Apack,
    const unsigned short* __restrict__ Bpack,
    unsigned short* __restrict__ partials16,
    const float* __restrict__ vpart, float* __restrict__ CCX,
    const float* __restrict__ beta, const float* __restrict__ theta,
    const float* __restrict__ Jccx,
    unsigned short* __restrict__ Xbpack,
    float* __restrict__ Rg_ws, float* __restrict__ tA_ws)
{
    __shared__ __align__(16) char smem[2 * 7680 + 2 * 20480];   // 56320
    const int bid = blockIdx.x;
    const int t = threadIdx.x;

    if (bid >= NGEMM) {
        if (bid < NGEMM + 8) {
            const int tid = (bid - NGEMM) * 256 + t;
            if (tid < 456 * 4) {
                float s = 0.f;
                #pragma unroll 9
                for (int ch = 0; ch < NVCH; ++ch)
                    s += vpart[(size_t)ch * VPROW + tid];
                const int col = tid >> 2, q = tid & 3;
                if (q < 3) {
                    CCX[col * 3 + q] = s;
                } else {
                    CCX[(size_t)218 * RL + col * 3 + 0] = s;
                    CCX[(size_t)218 * RL + col * 3 + 1] = s;
                    CCX[(size_t)218 * RL + col * 3 + 2] = s;
                }
            }
            return;
        }
        float* F = (float*)smem;
        float* xs = F;                       // 218
        float (*Rl)[9] = (float(*)[9])(F + 224);
        float (*Rg)[9] = (float(*)[9])(F + 440);
        float (*tg)[3] = (float(*)[3])(F + 656);
        float (*tA)[3] = (float(*)[3])(F + 728);
        float (*Jl)[3] = (float(*)[3])(F + 800);
        const int b = bid - (NGEMM + 8);

        if (t < 24) {
            const int i = t;
            const float tx = theta[b * 72 + 3 * i + 0];
            const float ty = theta[b * 72 + 3 * i + 1];
            const float tz = theta[b * 72 + 3 * i + 2];
            const float ax = tx + 1e-8f, ay = ty + 1e-8f, az = tz + 1e-8f;
            const float angle = sqrtf(ax * ax + ay * ay + az * az);
            const float half = 0.5f * angle;
            const float sh = sinf(half), chh = cosf(half);
            const float inv = 1.f / angle;
            float qw = chh, qx = sh * tx * inv, qy = sh * ty * inv, qz = sh * tz * inv;
            const float rn = 1.f / sqrtf(qw * qw + qx * qx + qy * qy + qz * qz);
            qw *= rn; qx *= rn; qy *= rn; qz *= rn;
            float R[9];
            R[0] = 1.f - 2.f * (qy * qy + qz * qz);
            R[1] = 2.f * (qx * qy - qw * qz);
            R[2] = 2.f * (qx * qz + qw * qy);
            R[3] = 2.f * (qx * qy + qw * qz);
            R[4] = 1.f - 2.f * (qx * qx + qz * qz);
            R[5] = 2.f * (qy * qz - qw * qx);
            R[6] = 2.f * (qx * qz - qw * qy);
            R[7] = 2.f * (qy * qz + qw * qx);
            R[8] = 1.f - 2.f * (qx * qx + qy * qy);
            #pragma unroll
            for (int e = 0; e < 9; ++e) Rl[i][e] = R[e];
            if (i >= 1) {
                #pragma unroll
                for (int e = 0; e < 9; ++e)
                    xs[11 + (i - 1) * 9 + e] = R[e] - ((e == 0 || e == 4 || e == 8) ? 1.f : 0.f);
            }
        } else if (t == 24) {
            xs[0] = 1.f;
        } else if (t >= 25 && t < 35) {
            xs[t - 24] = beta[b * NB + (t - 25)];
        }
        __syncthreads();

        if (t < 72) {
            const int jj = t / 3, c = t - (t / 3) * 3;
            float a = 0.f;
            #pragma unroll
            for (int r = 0; r <= 10; ++r)
                a += xs[r] * Jccx[r * 72 + jj * 3 + c];
            Jl[jj][c] = a;
        }
        __syncthreads();

        for (int lv = 0; lv < 9; ++lv) {
            const int beg = c_LOFF[lv];
            const int cnt = c_LOFF[lv + 1] - beg;
            if (t < cnt * 12) {
                const int li = t / 12, e = t - li * 12;
                const int j = beg + li;
                const int r = e >> 2, cc = e & 3;
                if (lv == 0) {
                    if (cc < 3) Rg[0][r * 3 + cc] = Rl[0][r * 3 + cc] * ((cc == 0) ? 1.f : -1.f);
                    else        tg[0][r] = Jl[0][r];
                } else {
                    const int p = c_PAR[j];
                    if (cc < 3) {
                        Rg[j][r * 3 + cc] = Rg[p][r * 3 + 0] * Rl[j][0 + cc]
                                          + Rg[p][r * 3 + 1] * Rl[j][3 + cc]
                                          + Rg[p][r * 3 + 2] * Rl[j][6 + cc];
                    } else {
                        const float t0 = Jl[j][0] - Jl[p][0];
                        const float t1 = Jl[j][1] - Jl[p][1];
                        const float t2 = Jl[j][2] - Jl[p][2];
                        tg[j][r] = Rg[p][r * 3 + 0] * t0 + Rg[p][r * 3 + 1] * t1
                                 + Rg[p][r * 3 + 2] * t2 + tg[p][r];
                    }
                }
            }
            __syncthreads();
        }

        if (t < 72) {
            const int i = t / 3, c = t - (t / 3) * 3;
            tA[i][c] = tg[i][c] - (Rg[i][c * 3 + 0] * Jl[i][0]
                                 + Rg[i][c * 3 + 1] * Jl[i][1]
                                 + Rg[i][c * 3 + 2] * Jl[i][2]);
        }
        __syncthreads();

        if (t < 224) {                   // k = t: 0..216 real, 217..223 ZERO pad
            const unsigned short hv = (t < 217) ? f2bf(xs[t + 1]) : (unsigned short)0;
            const int bt = b >> 5, brow = b & 31, kc = t >> 5, kk = t & 31;
            Xbpack[((size_t)(bt * 7 + kc) * 32 + brow) * 40 + kk] = hv;
        }
        if (t < 216) Rg_ws[(size_t)b * 216 + t] = ((const float*)Rg)[t];
        if (t < 72)  tA_ws[(size_t)b * 72 + t]  = ((const float*)tA)[t];
        return;
    }

    // ------------------------------ GEMM ----------------------------------
    const int ks = bid % KS2;
    const int nt = (bid / KS2) & 1;
    const int mt2 = bid / (KS2 * NT);
    const int w4 = t >> 6;
    const int lane15 = t & 15;
    const int kg = (t >> 4) & 3;
    const int kc0 = ks * KCP2;

    f32x4 acc[6][4];
    #pragma unroll
    for (int mf = 0; mf < 6; ++mf)
        #pragma unroll
        for (int nf = 0; nf < 4; ++nf) acc[mf][nf] = (f32x4){0.f, 0.f, 0.f, 0.f};

#define STAGE2(kc, buf) do { \
        _Pragma("unroll") \
        for (int q = 0; q < 3; ++q) { \
            if (t < 160) \
                GLOAD_LDS16((const char*)Apack + ((size_t)((3 * mt2 + q) * KC + (kc))) * 2560 + t * 16, \
                            smem + (buf) * 7680 + q * 2560 + (t >> 6) * 1024); \
        } \
        _Pragma("unroll") \
        for (int it = 0; it < 5; ++it) \
            GLOAD_LDS16((const char*)Bpack + ((size_t)(nt * KC + (kc))) * 20480 + (it * 256 + t) * 16, \
                        smem + 15360 + (buf) * 20480 + it * 4096 + (t >> 6) * 1024); \
    } while (0)

    STAGE2(kc0, 0);
    asm volatile("s_waitcnt vmcnt(0)" ::: "memory");
    __syncthreads();

    for (int i = 0; i < KCP2; ++i) {
        const int cur = i & 1;
        if (i < KCP2 - 1) STAGE2(kc0 + i + 1, cur ^ 1);

        short8 af[6];
        #pragma unroll
        for (int mf = 0; mf < 6; ++mf)
            af[mf] = *reinterpret_cast<const short8*>(
                smem + cur * 7680 + (mf * 16 + lane15) * 80 + kg * 16);
        #pragma unroll
        for (int nf = 0; nf < 4; ++nf) {
            const short8 bf = *reinterpret_cast<const short8*>(
                smem + 15360 + cur * 20480 + (w4 * 64 + nf * 16 + lane15) * 80 + kg * 16);
            #pragma unroll
            for (int mf = 0; mf < 6; ++mf)
                acc[mf][nf] = __builtin_amdgcn_mfma_f32_16x16x32_bf16(af[mf], bf, acc[mf][nf], 0, 0, 0);
        }
        if (i < KCP2 - 1) {
            asm volatile("s_waitcnt vmcnt(0)" ::: "memory");
            __syncthreads();
        }
    }
#undef STAGE2

    #pragma unroll
    for (int mf = 0; mf < 6; ++mf)
        #pragma unroll
        for (int nf = 0; nf < 4; ++nf) {
            const int m = mt2 * 96 + mf * 16 + kg * 4;
            const int col = nt * 256 + w4 * 64 + nf * 16 + lane15;
            #pragma unroll
            for (int reg = 0; reg < 4; ++reg)
                partials16[((size_t)ks * MDIM + m + reg) * 512 + col] = f2bf(acc[mf][nf][reg]);
        }
}

// ---------------------------------------------------------------------------
// reduce: 336 blocks; sum 12 bf16 K-split partials in fp32 -> Cbpack bf16.
// (ROUND-24: bf16 partials; layout indices unchanged.)
// ---------------------------------------------------------------------------
__global__ __launch_bounds__(256) void reduce_k(
    const unsigned short* __restrict__ partials16,
    unsigned short* __restrict__ Cbpack)
{
    const int idx = blockIdx.x * 256 + threadIdx.x;
    const int m = idx >> 7;
    const int col = (idx & 127) * 4;
    float s[4] = {0.f, 0.f, 0.f, 0.f};
    #pragma unroll 6
    for (int ks = 0; ks < KS2; ++ks) {
        const u16x4 p = *reinterpret_cast<const u16x4*>(
            &partials16[((size_t)ks * MDIM + m) * 512 + col]);
        s[0] += bf2f(p.x); s[1] += bf2f(p.y); s[2] += bf2f(p.z); s[3] += bf2f(p.w);
    }
    if (m < 657 && col < NCOLS) {
        const int r = m / 3, c = m - (m / 3) * 3;
        if (r != 0 && r != 218) {
            const int k = r - 1;                  // 0..216
            const int kc2 = k >> 5, kk = k & 31;
            #pragma unroll
            for (int u = 0; u < 4; ++u) {
                const int colIdx = (col + u) * 3 + c;
                if (colIdx < MLCOLS) {
                    const int ct2 = colIdx >> 8, colrow = colIdx & 255;
                    Cbpack[((size_t)(ct2 * 7 + kc2) * 256 + colrow) * 40 + kk] = f2bf(s[u]);
                }
            }
        }
    }
}

// ---------------------------------------------------------------------------
// mgemm_mfma: 32b x 64col tiles, 352 blocks. (Verified round 23.)
// ---------------------------------------------------------------------------
__global__ __launch_bounds__(256) void mgemm_mfma(
    const unsigned short* __restrict__ Xbpack,
    const unsigned short* __restrict__ Cbpack,
    const float* __restrict__ CCX,
    float* __restrict__ Ml)
{
    __shared__ __align__(16) char smem[2 * 2560 + 2 * 5120];   // 15360
    const int AOFF[2] = {0, 2560};
    const int BOFF[2] = {5120, 5120 + 5120};
    const int bid = blockIdx.x;
    const int ctp = bid % 22;          // 0..21 (64-col tiles)
    const int bt = bid / 22;           // 0..15
    const int t = threadIdx.x;
    const int w = t >> 6;
    const int lane15 = t & 15;
    const int kg = (t >> 4) & 3;
    const int mrow0 = (w & 1) * 16;
    const int ncol0 = (w >> 1) * 32;   // 2 col halves of 32

    const int ct2 = ctp >> 2;
    const size_t bsub = (size_t)(ctp & 3) * 64 * 80;   // byte offset of 64-row quarter

#define MSTG(kc, buf) do { \
        const char* ga = (const char*)Xbpack + ((size_t)(bt * 7 + (kc))) * 2560; \
        const char* gb = (const char*)Cbpack + ((size_t)(ct2 * 7 + (kc))) * 20480 + bsub; \
        if (t < 160) GLOAD_LDS16(ga + t * 16, smem + AOFF[buf] + (t >> 6) * 1024); \
        _Pragma("unroll") \
        for (int it = 0; it < 2; ++it) { \
            const int i_ = t + it * 256; \
            if (i_ < 320) \
                GLOAD_LDS16(gb + i_ * 16, smem + BOFF[buf] + (i_ >> 6) * 1024); \
        } \
    } while (0)

    f32x4 acc[2];
    #pragma unroll
    for (int f = 0; f < 2; ++f) acc[f] = (f32x4){0.f, 0.f, 0.f, 0.f};

    MSTG(0, 0);
    asm volatile("s_waitcnt vmcnt(0)" ::: "memory");
    __syncthreads();

    for (int i = 0; i < 7; ++i) {
        const int cur = i & 1;
        if (i < 6) MSTG(i + 1, cur ^ 1);

        const short8 af = *reinterpret_cast<const short8*>(
            smem + AOFF[cur] + (mrow0 + lane15) * 80 + kg * 16);
        #pragma unroll
        for (int f = 0; f < 2; ++f) {
            const short8 bf = *reinterpret_cast<const short8*>(
                smem + BOFF[cur] + (ncol0 + f * 16 + lane15) * 80 + kg * 16);
            acc[f] = __builtin_amdgcn_mfma_f32_16x16x32_bf16(af, bf, acc[f], 0, 0, 0);
        }
        if (i < 6) {
            asm volatile("s_waitcnt vmcnt(0)" ::: "memory");
            __syncthreads();
        }
    }
#undef MSTG

    #pragma unroll
    for (int f = 0; f < 2; ++f) {
        const int colp = ctp * 64 + ncol0 + f * 16 + lane15;
        if (colp < MLCOLS) {
            const float base = CCX[colp];          // row 0 (fp32 exact, xs[0]=1)
            const int bb = bt * 32 + mrow0 + kg * 4;
            #pragma unroll
            for (int reg = 0; reg < 4; ++reg)
                Ml[(size_t)(bb + reg) * MLCOLS + colp] = acc[f][reg] + base;
        }
    }
}

// ---------------------------------------------------------------------------
// joints: one block per b, 256 threads. (Verified.)
// ---------------------------------------------------------------------------
__global__ __launch_bounds__(256) void joints_k(
    const float* __restrict__ Ml, const float* __restrict__ Rg_ws,
    const float* __restrict__ tA_ws, const float* __restrict__ CCX,
    float* __restrict__ out)
{
    __shared__ float Mls[1368];
    __shared__ float Wj[1368];
    __shared__ float Rgs[216];
    __shared__ float tAs[72];
    const int b = blockIdx.x;
    const int t = threadIdx.x;

    for (int i = t; i < 342; i += 256) {
        reinterpret_cast<float4*>(Mls)[i] =
            reinterpret_cast<const float4*>(Ml + (size_t)b * 1368)[i];
        reinterpret_cast<float4*>(Wj)[i] =
            reinterpret_cast<const float4*>(CCX + (size_t)218 * RL)[i];
    }
    if (t < 216) Rgs[t] = Rg_ws[(size_t)b * 216 + t];
    if (t < 72)  tAs[t] = tA_ws[(size_t)b * 72 + t];
    __syncthreads();

    if (t < 57) {
        const int j = t / 3, c = t - (t / 3) * 3;
        float a = 0.f;
        #pragma unroll
        for (int i = 0; i < 24; ++i) {
            const int mb = (j * 24 + i) * 3;
            a += Rgs[i * 9 + c * 3 + 0] * Mls[mb + 0]
               + Rgs[i * 9 + c * 3 + 1] * Mls[mb + 1]
               + Rgs[i * 9 + c * 3 + 2] * Mls[mb + 2]
               + tAs[i * 3 + c] * Wj[mb];
        }
        out[b * 57 + t] = a;
    }
}

extern "C" void kernel_launch(void* const* d_in, const int* in_sizes, int n_in,
                              void* d_out, int out_size, void* d_ws, size_t ws_size,
                              hipStream_t stream) {
    const float* beta  = (const float*)d_in[0];
    const float* theta = (const float*)d_in[1];
    const float* vt    = (const float*)d_in[2];
    const float* sd    = (const float*)d_in[3];
    const float* pd    = (const float*)d_in[4];
    const float* Jreg  = (const float*)d_in[5];
    const float* jr    = (const float*)d_in[6];
    const float* w     = (const float*)d_in[7];
    float* outp = (float*)d_out;

    // ws layout (floats): CCX | partials(12, bf16 in same-size region) | Apack |
    //                     Bpack | Jccx | Rg | tA | vpart | Ml | Xbpack | Cbpack
    float* CCX = (float*)d_ws;
    float* partials = CCX + CCX_ELEMS;
    unsigned short* partials16 = (unsigned short*)partials;
    unsigned short* Apack = (unsigned short*)(partials + (size_t)KS2 * MDIM * 512);
    unsigned short* Bpack = Apack + (size_t)MT * KC * AIMG;
    float* Jccx  = (float*)(Bpack + (size_t)NT * KC * BIMG);
    float* Rg_ws = Jccx + 792;
    float* tA_ws = Rg_ws + 512 * 216;
    float* vpart = tA_ws + 512 * 72;
    float* Ml    = vpart + (size_t)NVCH * VPROW;
    unsigned short* Xbpack = (unsigned short*)(Ml + (size_t)512 * MLCOLS);
    unsigned short* Cbpack = Xbpack + (size_t)16 * 7 * 32 * 40;

    prep<<<491, 256, 0, stream>>>(vt, sd, pd, Jreg, jr, w, Apack, Bpack, CCX, Jccx, vpart);
    gemmchain<<<NGEMM + 8 + 512, 256, 0, stream>>>(Apack, Bpack, partials16, vpart, CCX,
                                                   beta, theta, Jccx,
                                                   Xbpack, Rg_ws, tA_ws);
    reduce_k<<<336, 256, 0, stream>>>(partials16, Cbpack);
    mgemm_mfma<<<352, 256, 0, stream>>>(Xbpack, Cbpack, CCX, Ml);
    joints_k<<<512, 256, 0, stream>>>(Ml, Rg_ws, tA_ws, CCX, outp);
}